// Round 9
// baseline (433.230 us; speedup 1.0000x reference)
//
#include <hip/hip_runtime.h>
#include <hip/hip_bf16.h>
#include <math.h>

#define TQ 100
#define SS 4096
#define BB 32
#define EE 256
#define HH 8
#define FF 2048
#define DHH 32
#define LNEPS 1e-5f

typedef __attribute__((ext_vector_type(8))) short bf16x8;
typedef __attribute__((ext_vector_type(4))) short bf16x4;
typedef __attribute__((ext_vector_type(4))) float f32x4;

__device__ inline unsigned short f2bfu(float f) {
    __hip_bfloat16 h = __float2bfloat16(f);
    return *reinterpret_cast<unsigned short*>(&h);
}

#define PBM 64
#define PBK 32
#define PLDP 40
#define TLP 268

// ---------------- fused weight fp32->bf16 convert (10 segments, 1 launch) ----------------
__global__ __launch_bounds__(256)
void cvt_all(const float* s0, const float* s1, const float* s2, const float* s3,
             const float* s4, const float* s5, const float* s6, const float* s7,
             const float* s8, const float* s9,
             unsigned short* d0, unsigned short* d1, unsigned short* d2, unsigned short* d3,
             unsigned short* d4, unsigned short* d5, unsigned short* d6, unsigned short* d7,
             unsigned short* d8, unsigned short* d9)
{
    const int bi = blockIdx.x;
    const float* s; unsigned short* d; int base;
    if (bi < 512) {
        const int seg = bi >> 6;
        base = (bi & 63) * 1024;
        switch (seg) {
            case 0: s = s0; d = d0; break;
            case 1: s = s1; d = d1; break;
            case 2: s = s2; d = d2; break;
            case 3: s = s3; d = d3; break;
            case 4: s = s4; d = d4; break;
            case 5: s = s5; d = d5; break;
            case 6: s = s6; d = d6; break;
            default: s = s7; d = d7; break;
        }
    } else {
        const int r = bi - 512;
        base = (r & 511) * 1024;
        if (r >> 9) { s = s9; d = d9; } else { s = s8; d = d8; }
    }
    const int i = base + threadIdx.x * 4;
    float4 v = *(const float4*)(s + i);
    ushort4 ov;
    ov.x = f2bfu(v.x); ov.y = f2bfu(v.y); ov.z = f2bfu(v.z); ov.w = f2bfu(v.w);
    *(ushort4*)(d + i) = ov;
}

// ---------------- fused K + V^T projection: 4 waves, m-tile 32, W direct from L2 ----------------
// waves 0-1: K (n 0-127 / 128-255) = (enc+ep)@Wk^T + bk  -> rows layout
// waves 2-3: V = enc@Wv^T + bv  -> V^T layout
// A (HBM fp32) staged in LDS double-buffered; W fragments loaded straight from global (L2).
__global__ __launch_bounds__(256, 4)
void proj_kv(const float* __restrict__ enc, const float* __restrict__ ep,
             const __hip_bfloat16* __restrict__ Wk, const float* __restrict__ bk,
             const __hip_bfloat16* __restrict__ Wv, const float* __restrict__ bv,
             __hip_bfloat16* __restrict__ Kout, __hip_bfloat16* __restrict__ Vtout)
{
    __shared__ short lds[32 * TLP];   // 17.2 KB; A-dbuf (5120 shorts) overlays low region
    const int tid = threadIdx.x;
    const int m0 = blockIdx.x * 32;
    const int b = m0 >> 12;
    const int s0 = m0 & (SS - 1);

    // A staging: 32 rows x 32 k fp32 per stream; 1 float4/stream/thread
    const int arr = tid >> 3;           // 0..31
    const int arc = (tid & 7) << 2;     // 0..28
    const long long abase = ((long long)(s0 + arr) * BB + b) * EE + arc;

    const int w = tid >> 6, l = tid & 63;
    const int mat = w >> 1;             // 0 = K, 1 = V
    const int wn0 = (w & 1) * 128;
    const int lr16 = l & 15, lk8 = (l >> 4) * 8;
    const __hip_bfloat16* Wm = mat ? Wv : Wk;
    // per-lane W row base: 16B contiguous per lane, full 64B sectors across lane groups
    const long long wlbase = (long long)(wn0 + lr16) * EE + lk8;

    f32x4 acc[2][8] = {};

    // prologue: load + cvt + write A buf 0
    float4 a0 = *(const float4*)(enc + abase);
    float4 e0 = *(const float4*)(ep + abase);
    {
        bf16x4 pk, pv;
        pk[0] = (short)f2bfu(a0.x + e0.x); pk[1] = (short)f2bfu(a0.y + e0.y);
        pk[2] = (short)f2bfu(a0.z + e0.z); pk[3] = (short)f2bfu(a0.w + e0.w);
        pv[0] = (short)f2bfu(a0.x); pv[1] = (short)f2bfu(a0.y);
        pv[2] = (short)f2bfu(a0.z); pv[3] = (short)f2bfu(a0.w);
        *(bf16x4*)&lds[arr * PLDP + arc] = pk;
        *(bf16x4*)&lds[2560 + arr * PLDP + arc] = pv;
    }
    __syncthreads();

    int p = 0;
    for (int k0 = 0; k0 < EE; k0 += PBK) {
        // prefetch next A slice (HBM) early
        float4 a1, e1;
        const bool more = (k0 + PBK < EE);
        if (more) {
            a1 = *(const float4*)(enc + abase + k0 + PBK);
            e1 = *(const float4*)(ep + abase + k0 + PBK);
        }

        const int ab = (mat ? 2560 : 0) + p * 1280;
        bf16x8 af0 = *(const bf16x8*)&lds[ab + lr16 * PLDP + lk8];
        bf16x8 af1 = *(const bf16x8*)&lds[ab + (16 + lr16) * PLDP + lk8];

        // W direct from L2, two groups of 4 to bound VGPR
        bf16x8 wr[4];
        #pragma unroll
        for (int j = 0; j < 4; ++j)
            wr[j] = *(const bf16x8*)(Wm + wlbase + (long long)(j * 16) * EE + k0);
        #pragma unroll
        for (int j = 0; j < 4; ++j) {
            acc[0][j] = __builtin_amdgcn_mfma_f32_16x16x32_bf16(af0, wr[j], acc[0][j], 0, 0, 0);
            acc[1][j] = __builtin_amdgcn_mfma_f32_16x16x32_bf16(af1, wr[j], acc[1][j], 0, 0, 0);
        }
        #pragma unroll
        for (int j = 0; j < 4; ++j)
            wr[j] = *(const bf16x8*)(Wm + wlbase + (long long)((j + 4) * 16) * EE + k0);
        #pragma unroll
        for (int j = 0; j < 4; ++j) {
            acc[0][j + 4] = __builtin_amdgcn_mfma_f32_16x16x32_bf16(af0, wr[j], acc[0][j + 4], 0, 0, 0);
            acc[1][j + 4] = __builtin_amdgcn_mfma_f32_16x16x32_bf16(af1, wr[j], acc[1][j + 4], 0, 0, 0);
        }

        // stage next A into the other buffer (safe: readers of buf p are pre-barrier)
        if (more) {
            bf16x4 pk, pv;
            pk[0] = (short)f2bfu(a1.x + e1.x); pk[1] = (short)f2bfu(a1.y + e1.y);
            pk[2] = (short)f2bfu(a1.z + e1.z); pk[3] = (short)f2bfu(a1.w + e1.w);
            pv[0] = (short)f2bfu(a1.x); pv[1] = (short)f2bfu(a1.y);
            pv[2] = (short)f2bfu(a1.z); pv[3] = (short)f2bfu(a1.w);
            *(bf16x4*)&lds[(p ^ 1) * 1280 + arr * PLDP + arc] = pk;
            *(bf16x4*)&lds[2560 + (p ^ 1) * 1280 + arr * PLDP + arc] = pv;
        }
        __syncthreads();
        p ^= 1;
    }

    // ---- epilogue: K tile then V tile through the shared 32x268 staging buffer ----
    short (*tile)[TLP] = (short(*)[TLP])lds;
    const int q4 = (l >> 4) * 4;

    if (mat == 0) {
        #pragma unroll
        for (int i = 0; i < 2; ++i)
            #pragma unroll
            for (int j = 0; j < 8; ++j) {
                const int n = wn0 + j * 16 + lr16;
                const float bi = bk[n];
                #pragma unroll
                for (int r = 0; r < 4; ++r)
                    tile[i * 16 + q4 + r][n] = (short)f2bfu(acc[i][j][r] + bi);
            }
    }
    __syncthreads();
    // drain K: 32 rows x 256 cols; wave w -> rows w*8..+7, 64 lanes x 8B per row
    #pragma unroll
    for (int it = 0; it < 8; ++it) {
        const int r2 = w * 8 + it;
        ushort4 v = *(const ushort4*)&tile[r2][l * 4];
        *(ushort4*)(Kout + (long long)(m0 + r2) * EE + l * 4) = v;
    }
    __syncthreads();
    if (mat == 1) {
        #pragma unroll
        for (int i = 0; i < 2; ++i)
            #pragma unroll
            for (int j = 0; j < 8; ++j) {
                const int n = wn0 + j * 16 + lr16;
                const float bi = bv[n];
                #pragma unroll
                for (int r = 0; r < 4; ++r)
                    tile[i * 16 + q4 + r][n] = (short)f2bfu(acc[i][j][r] + bi);
            }
    }
    __syncthreads();
    // drain V^T: wave w -> n = w*64..+63; per iter 2 n-rows x 32 s (64B per n-row)
    #pragma unroll
    for (int nn = 0; nn < 32; ++nn) {
        const int n = w * 64 + nn * 2 + (l >> 5);
        const int s = l & 31;
        unsigned short v = (unsigned short)tile[s][n];
        *((unsigned short*)Vtout + (long long)(b * EE + n) * SS + s0 + s) = v;
    }
}

// ---------------- small MFMA GEMM: 32m x 128n tile, 128 threads ----------------
template<int A1G, int A2Q, int A1BF, int OBF, int RELU>
__global__ __launch_bounds__(128)
void mfma_gemm2(const void* __restrict__ A1v, const float* __restrict__ A2,
                const __hip_bfloat16* __restrict__ Wb, const float* __restrict__ bias,
                void* __restrict__ outv, int N, int K, float scale)
{
    __shared__ short As[32][PLDP];
    __shared__ short Bs[128][PLDP];
    const int tid = threadIdx.x;
    const int m0 = blockIdx.x * 32;
    const int n0 = blockIdx.y * 128;
    const int rr = tid >> 2;
    const int rc = (tid & 3) << 3;
    const int row = m0 + rr;

    long long a2row = 0;
    if (A1G || A2Q) {
        int bq = row / TQ, tq = row - bq * TQ;
        a2row = ((long long)(tq * BB + bq)) * EE;
    }
    const long long a1row = A1G ? a2row : (long long)row * K;

    const int wv = tid >> 6, l = tid & 63;
    const int wm0 = wv * 16;
    const int lr16 = l & 15, lk8 = (l >> 4) * 8;

    f32x4 acc[8] = {};

    for (int k0 = 0; k0 < K; k0 += PBK) {
        bf16x8 apack;
        if (A1BF) {
            apack = *(const bf16x8*)((const __hip_bfloat16*)A1v + a1row + k0 + rc);
        } else {
            const float* A1 = (const float*)A1v;
            float4 a0 = *(const float4*)(A1 + a1row + k0 + rc);
            float4 a1 = *(const float4*)(A1 + a1row + k0 + rc + 4);
            if (A2Q) {
                float4 e0 = *(const float4*)(A2 + a2row + k0 + rc);
                float4 e1 = *(const float4*)(A2 + a2row + k0 + rc + 4);
                a0.x += e0.x; a0.y += e0.y; a0.z += e0.z; a0.w += e0.w;
                a1.x += e1.x; a1.y += e1.y; a1.z += e1.z; a1.w += e1.w;
            }
            apack[0] = (short)f2bfu(a0.x); apack[1] = (short)f2bfu(a0.y);
            apack[2] = (short)f2bfu(a0.z); apack[3] = (short)f2bfu(a0.w);
            apack[4] = (short)f2bfu(a1.x); apack[5] = (short)f2bfu(a1.y);
            apack[6] = (short)f2bfu(a1.z); apack[7] = (short)f2bfu(a1.w);
        }

        bf16x8 wreg[4];
        #pragma unroll
        for (int it = 0; it < 4; ++it)
            wreg[it] = *(const bf16x8*)(Wb + (long long)(n0 + rr + it * 32) * K + k0 + rc);

        __syncthreads();
        *(bf16x8*)&As[rr][rc] = apack;
        #pragma unroll
        for (int it = 0; it < 4; ++it)
            *(bf16x8*)&Bs[rr + it * 32][rc] = wreg[it];
        __syncthreads();

        bf16x8 af = *(const bf16x8*)&As[wm0 + lr16][lk8];
        #pragma unroll
        for (int j = 0; j < 8; ++j) {
            bf16x8 bfr = *(const bf16x8*)&Bs[j * 16 + lr16][lk8];
            acc[j] = __builtin_amdgcn_mfma_f32_16x16x32_bf16(af, bfr, acc[j], 0, 0, 0);
        }
    }

    const int q4 = (l >> 4) * 4;
    #pragma unroll
    for (int j = 0; j < 8; ++j) {
        const int n = n0 + j * 16 + lr16;
        const float bi = bias[n];
        #pragma unroll
        for (int r = 0; r < 4; ++r) {
            float v = (acc[j][r] + bi) * scale;
            if (RELU) v = fmaxf(v, 0.f);
            const long long oidx = (long long)(m0 + wm0 + q4 + r) * N + n;
            if (OBF) ((__hip_bfloat16*)outv)[oidx] = __float2bfloat16(v);
            else     ((float*)outv)[oidx] = v;
        }
    }
}

// ---------------- fused SA QKV projection ----------------
__global__ __launch_bounds__(128)
void qkv_sa(const float* __restrict__ hs1, const float* __restrict__ qp,
            const __hip_bfloat16* __restrict__ Wq, const float* __restrict__ bq,
            const __hip_bfloat16* __restrict__ Wk, const float* __restrict__ bk,
            const __hip_bfloat16* __restrict__ Wv, const float* __restrict__ bv,
            __hip_bfloat16* __restrict__ Qs, __hip_bfloat16* __restrict__ Ks,
            __hip_bfloat16* __restrict__ Vt, int SVT, float qscale)
{
    __shared__ short Aq[32][PLDP];
    __shared__ short Av[32][PLDP];
    __shared__ short Bq[128][PLDP];
    __shared__ short Bk[128][PLDP];
    __shared__ short Bv[128][PLDP];
    const int tid = threadIdx.x;
    const int m0 = blockIdx.x * 32;
    const int n0 = blockIdx.y * 128;
    const int rr = tid >> 2;
    const int rc = (tid & 3) << 3;
    const int row = m0 + rr;
    const int bq_ = row / TQ, tq = row - bq_ * TQ;
    const long long a1row = (long long)row * EE;
    const long long a2row = ((long long)(tq * BB + bq_)) * EE;

    const int wv = tid >> 6, l = tid & 63;
    const int wm0 = wv * 16;
    const int lr16 = l & 15, lk8 = (l >> 4) * 8;

    f32x4 aq[8] = {}, ak[8] = {}, av[8] = {};

    for (int k0 = 0; k0 < EE; k0 += PBK) {
        float4 a0 = *(const float4*)(hs1 + a1row + k0 + rc);
        float4 a1 = *(const float4*)(hs1 + a1row + k0 + rc + 4);
        float4 e0 = *(const float4*)(qp + a2row + k0 + rc);
        float4 e1 = *(const float4*)(qp + a2row + k0 + rc + 4);
        bf16x8 pq, pv;
        pv[0] = (short)f2bfu(a0.x); pv[1] = (short)f2bfu(a0.y);
        pv[2] = (short)f2bfu(a0.z); pv[3] = (short)f2bfu(a0.w);
        pv[4] = (short)f2bfu(a1.x); pv[5] = (short)f2bfu(a1.y);
        pv[6] = (short)f2bfu(a1.z); pv[7] = (short)f2bfu(a1.w);
        pq[0] = (short)f2bfu(a0.x + e0.x); pq[1] = (short)f2bfu(a0.y + e0.y);
        pq[2] = (short)f2bfu(a0.z + e0.z); pq[3] = (short)f2bfu(a0.w + e0.w);
        pq[4] = (short)f2bfu(a1.x + e1.x); pq[5] = (short)f2bfu(a1.y + e1.y);
        pq[6] = (short)f2bfu(a1.z + e1.z); pq[7] = (short)f2bfu(a1.w + e1.w);

        bf16x8 wq8[4], wk8[4], wv8[4];
        #pragma unroll
        for (int it = 0; it < 4; ++it) {
            const long long wr = (long long)(n0 + rr + it * 32) * EE + k0 + rc;
            wq8[it] = *(const bf16x8*)(Wq + wr);
            wk8[it] = *(const bf16x8*)(Wk + wr);
            wv8[it] = *(const bf16x8*)(Wv + wr);
        }

        __syncthreads();
        *(bf16x8*)&Aq[rr][rc] = pq;
        *(bf16x8*)&Av[rr][rc] = pv;
        #pragma unroll
        for (int it = 0; it < 4; ++it) {
            *(bf16x8*)&Bq[rr + it * 32][rc] = wq8[it];
            *(bf16x8*)&Bk[rr + it * 32][rc] = wk8[it];
            *(bf16x8*)&Bv[rr + it * 32][rc] = wv8[it];
        }
        __syncthreads();

        bf16x8 afq = *(const bf16x8*)&Aq[wm0 + lr16][lk8];
        bf16x8 afv = *(const bf16x8*)&Av[wm0 + lr16][lk8];
        #pragma unroll
        for (int j = 0; j < 8; ++j) {
            bf16x8 b1 = *(const bf16x8*)&Bq[j * 16 + lr16][lk8];
            bf16x8 b2 = *(const bf16x8*)&Bk[j * 16 + lr16][lk8];
            bf16x8 b3 = *(const bf16x8*)&Bv[j * 16 + lr16][lk8];
            aq[j] = __builtin_amdgcn_mfma_f32_16x16x32_bf16(afq, b1, aq[j], 0, 0, 0);
            ak[j] = __builtin_amdgcn_mfma_f32_16x16x32_bf16(afq, b2, ak[j], 0, 0, 0);
            av[j] = __builtin_amdgcn_mfma_f32_16x16x32_bf16(afv, b3, av[j], 0, 0, 0);
        }
    }

    const int q4 = (l >> 4) * 4;
    #pragma unroll
    for (int j = 0; j < 8; ++j) {
        const int n = n0 + j * 16 + lr16;
        const float b1 = bq[n], b2 = bk[n], b3 = bv[n];
        #pragma unroll
        for (int r = 0; r < 4; ++r) {
            const int m = m0 + wm0 + q4 + r;
            Qs[(long long)m * EE + n] = __float2bfloat16((aq[j][r] + b1) * qscale);
            Ks[(long long)m * EE + n] = __float2bfloat16(ak[j][r] + b2);
            const int bb = m / TQ, tt = m - bb * TQ;
            Vt[(long long)(bb * EE + n) * SVT + tt] = __float2bfloat16(av[j][r] + b3);
        }
    }
}

// ---------------- MFMA flash attention: 4 waves, 64 q/block, XCD-chunked swizzle ----------------
#define KVB 32
#define LDP 40

__global__ __launch_bounds__(256, 2)
void flash_mfma(const __hip_bfloat16* __restrict__ Qg,
                const __hip_bfloat16* __restrict__ Kg,
                const __hip_bfloat16* __restrict__ Vtg,
                const float* __restrict__ mask,
                __hip_bfloat16* __restrict__ O,
                int Skv, int SVT)
{
    __shared__ short Ks[2][KVB][LDP];
    __shared__ short Vs[2][KVB][LDP];
    const int tid = threadIdx.x;
    const int l = tid & 63;
    const int g = l >> 4, q16 = l & 15;
    const int chunk = gridDim.x >> 3;
    const int logical = (blockIdx.x & 7) * chunk + (blockIdx.x >> 3);
    const int qb = logical & 1;
    const int bh = logical >> 1;
    const int h = bh & (HH - 1), b = bh >> 3;
    const int q0 = qb * 64 + (tid >> 6) * 16;

    int qc = q0 + q16; if (qc >= TQ) qc = TQ - 1;
    const bf16x8 qfrag = *(const bf16x8*)(Qg + ((long long)(b * TQ + qc)) * EE + h * DHH + g * 8);

    const int srow = tid >> 3;
    const int sseg = (tid & 7) * 4;
    const long long kbase = ((long long)b * Skv) * EE + h * DHH;
    const long long vbase = ((long long)(b * EE + h * DHH)) * SVT;
    const float* mrowp = mask ? mask + ((long long)bh * TQ + qc) * Skv : nullptr;

    f32x4 oacc[2] = {{0.f,0.f,0.f,0.f},{0.f,0.f,0.f,0.f}};
    float mrun = -1e30f, lrun = 0.f;
    const f32x4 zero = {0.f,0.f,0.f,0.f};

    int s_ld = srow; if (s_ld >= Skv) s_ld = Skv - 1;
    bf16x4 kreg = *(const bf16x4*)(Kg + kbase + (long long)s_ld * EE + sseg);
    bf16x4 vreg = *(const bf16x4*)(Vtg + vbase + (long long)srow * SVT + sseg);
    float4 mcur0, mcur1;
    if (mrowp) {
        mcur0 = *(const float4*)(mrowp + g * 4);
        mcur1 = *(const float4*)(mrowp + 16 + g * 4);
    }

    const int nround = (Skv + KVB - 1) / KVB;
    for (int r = 0; r < nround; ++r) {
        const int buf = r & 1;
        *(bf16x4*)&Ks[buf][srow][sseg] = kreg;
        *(bf16x4*)&Vs[buf][srow][sseg] = vreg;
        float4 mnx0, mnx1;
        if (r + 1 < nround) {
            int sn = (r + 1) * KVB + srow; if (sn >= Skv) sn = Skv - 1;
            kreg = *(const bf16x4*)(Kg + kbase + (long long)sn * EE + sseg);
            vreg = *(const bf16x4*)(Vtg + vbase + (long long)srow * SVT + (r + 1) * KVB + sseg);
            if (mrowp) {
                mnx0 = *(const float4*)(mrowp + (r + 1) * KVB + g * 4);
                mnx1 = *(const float4*)(mrowp + (r + 1) * KVB + 16 + g * 4);
            }
        }
        __syncthreads();

        const int s0 = r * KVB;
        f32x4 sT[2];
        #pragma unroll
        for (int t = 0; t < 2; ++t) {
            bf16x8 kf = *(const bf16x8*)&Ks[buf][t * 16 + q16][g * 8];
            sT[t] = __builtin_amdgcn_mfma_f32_16x16x32_bf16(kf, qfrag, zero, 0, 0, 0);
        }
        float sc[8];
        if (mrowp) {
            sc[0] = sT[0][0] + mcur0.x; sc[1] = sT[0][1] + mcur0.y;
            sc[2] = sT[0][2] + mcur0.z; sc[3] = sT[0][3] + mcur0.w;
            sc[4] = sT[1][0] + mcur1.x; sc[5] = sT[1][1] + mcur1.y;
            sc[6] = sT[1][2] + mcur1.z; sc[7] = sT[1][3] + mcur1.w;
        } else {
            #pragma unroll
            for (int t = 0; t < 2; ++t)
                #pragma unroll
                for (int rg = 0; rg < 4; ++rg) {
                    int s = s0 + t * 16 + g * 4 + rg;
                    sc[t*4+rg] = (s < Skv) ? sT[t][rg] : -1e30f;
                }
        }
        float tmax = sc[0];
        #pragma unroll
        for (int i = 1; i < 8; ++i) tmax = fmaxf(tmax, sc[i]);
        tmax = fmaxf(tmax, __shfl_xor(tmax, 16));
        tmax = fmaxf(tmax, __shfl_xor(tmax, 32));
        const float mn = fmaxf(mrun, tmax);
        const float corr = __expf(mrun - mn);
        mrun = mn;
        float ps = 0.f;
        bf16x8 pfrag;
        #pragma unroll
        for (int i = 0; i < 8; ++i) {
            float p = __expf(sc[i] - mn);
            ps += p;
            pfrag[i] = (short)f2bfu(p);
        }
        ps += __shfl_xor(ps, 16);
        ps += __shfl_xor(ps, 32);
        lrun = lrun * corr + ps;
        #pragma unroll
        for (int rg = 0; rg < 4; ++rg) {
            float c = __shfl(corr, g * 4 + rg);
            oacc[0][rg] *= c;
            oacc[1][rg] *= c;
        }
        #pragma unroll
        for (int T = 0; T < 2; ++T) {
            bf16x4 v0 = *(const bf16x4*)&Vs[buf][T * 16 + q16][g * 4];
            bf16x4 v1 = *(const bf16x4*)&Vs[buf][T * 16 + q16][16 + g * 4];
            bf16x8 vf;
            vf[0] = v0[0]; vf[1] = v0[1]; vf[2] = v0[2]; vf[3] = v0[3];
            vf[4] = v1[0]; vf[5] = v1[1]; vf[6] = v1[2]; vf[7] = v1[3];
            oacc[T] = __builtin_amdgcn_mfma_f32_16x16x32_bf16(pfrag, vf, oacc[T], 0, 0, 0);
        }
        mcur0 = mnx0; mcur1 = mnx1;
        __syncthreads();
    }

    float linv[4];
    #pragma unroll
    for (int rg = 0; rg < 4; ++rg)
        linv[rg] = 1.f / __shfl(lrun, g * 4 + rg);
    #pragma unroll
    for (int rg = 0; rg < 4; ++rg) {
        const int q = q0 + g * 4 + rg;
        if (q < TQ) {
            __hip_bfloat16* op = O + ((long long)(b * TQ + q)) * EE + h * DHH + q16;
            op[0]  = __float2bfloat16(oacc[0][rg] * linv[rg]);
            op[16] = __float2bfloat16(oacc[1][rg] * linv[rg]);
        }
    }
}

// ---------------- LayerNorm ----------------
template<int GATHER_RES, int OUT_T, int OUT_BF>
__global__ __launch_bounds__(256)
void ln_kernel(const float* __restrict__ res, const float* __restrict__ x,
               const float* __restrict__ gam, const float* __restrict__ bet,
               float* __restrict__ out, __hip_bfloat16* __restrict__ outb)
{
    __shared__ float r1[4], r2[4];
    const int m = blockIdx.x;
    const int k = threadIdx.x;
    const int b = m / TQ, t = m - b * TQ;
    const long long roff = GATHER_RES ? ((long long)(t * BB + b)) * EE : (long long)m * EE;
    float v = res[roff + k] + x[(long long)m * EE + k];
    float s = v;
    #pragma unroll
    for (int off = 32; off; off >>= 1) s += __shfl_down(s, off);
    if ((k & 63) == 0) r1[k >> 6] = s;
    __syncthreads();
    const float mu = (r1[0] + r1[1] + r1[2] + r1[3]) * (1.0f / EE);
    const float d = v - mu;
    float s2 = d * d;
    #pragma unroll
    for (int off = 32; off; off >>= 1) s2 += __shfl_down(s2, off);
    if ((k & 63) == 0) r2[k >> 6] = s2;
    __syncthreads();
    const float var = (r2[0] + r2[1] + r2[2] + r2[3]) * (1.0f / EE);
    const float o = d * rsqrtf(var + LNEPS) * gam[k] + bet[k];
    const long long ooff = OUT_T ? ((long long)(t * BB + b)) * EE : (long long)m * EE;
    out[ooff + k] = o;
    if (OUT_BF) outb[(long long)m * EE + k] = __float2bfloat16(o);
}

extern "C" void kernel_launch(void* const* d_in, const int* in_sizes, int n_in,
                              void* d_out, int out_size, void* d_ws, size_t ws_size,
                              hipStream_t stream)
{
    const float* hs    = (const float*)d_in[0];
    const float* qp    = (const float*)d_in[1];
    const float* enc   = (const float*)d_in[2];
    const float* ep    = (const float*)d_in[3];
    const float* mask  = (const float*)d_in[4];
    const float* ca_wq = (const float*)d_in[5];  const float* ca_bq = (const float*)d_in[6];
    const float* ca_wk = (const float*)d_in[7];  const float* ca_bk = (const float*)d_in[8];
    const float* ca_wv = (const float*)d_in[9];  const float* ca_bv = (const float*)d_in[10];
    const float* ca_wo = (const float*)d_in[11]; const float* ca_bo = (const float*)d_in[12];
    const float* sa_wq = (const float*)d_in[13]; const float* sa_bq = (const float*)d_in[14];
    const float* sa_wk = (const float*)d_in[15]; const float* sa_bk = (const float*)d_in[16];
    const float* sa_wv = (const float*)d_in[17]; const float* sa_bv = (const float*)d_in[18];
    const float* sa_wo = (const float*)d_in[19]; const float* sa_bo = (const float*)d_in[20];
    const float* ln1_g = (const float*)d_in[21]; const float* ln1_b = (const float*)d_in[22];
    const float* ln2_g = (const float*)d_in[23]; const float* ln2_b = (const float*)d_in[24];
    const float* ln3_g = (const float*)d_in[25]; const float* ln3_b = (const float*)d_in[26];
    const float* fc1_w = (const float*)d_in[27]; const float* fc1_b = (const float*)d_in[28];
    const float* fc2_w = (const float*)d_in[29]; const float* fc2_b = (const float*)d_in[30];

    const int MQ = BB * TQ;   // 3200
    const int MK = BB * SS;   // 131072
    const int SVT2 = 128;

    size_t off = 0;
    char* base = (char*)d_ws;
    auto alloc = [&](size_t bytes) -> void* {
        void* p = base + off; off = (off + bytes + 255) & ~(size_t)255; return p;
    };
    __hip_bfloat16* Kc  = (__hip_bfloat16*)alloc((size_t)MK * EE * 2);
    __hip_bfloat16* Vt  = (__hip_bfloat16*)alloc((size_t)BB * EE * SS * 2);
    __hip_bfloat16* Qc  = (__hip_bfloat16*)alloc((size_t)MQ * EE * 2);
    __hip_bfloat16* Qs  = (__hip_bfloat16*)alloc((size_t)MQ * EE * 2);
    __hip_bfloat16* Ks2 = (__hip_bfloat16*)alloc((size_t)MQ * EE * 2);
    __hip_bfloat16* Vt2 = (__hip_bfloat16*)alloc((size_t)BB * EE * SVT2 * 2);
    __hip_bfloat16* Wq1 = (__hip_bfloat16*)alloc((size_t)EE * EE * 2);
    __hip_bfloat16* Wkb = (__hip_bfloat16*)alloc((size_t)EE * EE * 2);
    __hip_bfloat16* Wvb = (__hip_bfloat16*)alloc((size_t)EE * EE * 2);
    __hip_bfloat16* Wo1 = (__hip_bfloat16*)alloc((size_t)EE * EE * 2);
    __hip_bfloat16* Wq2 = (__hip_bfloat16*)alloc((size_t)EE * EE * 2);
    __hip_bfloat16* Wk2 = (__hip_bfloat16*)alloc((size_t)EE * EE * 2);
    __hip_bfloat16* Wv2 = (__hip_bfloat16*)alloc((size_t)EE * EE * 2);
    __hip_bfloat16* Wo2 = (__hip_bfloat16*)alloc((size_t)EE * EE * 2);
    __hip_bfloat16* Wf1 = (__hip_bfloat16*)alloc((size_t)FF * EE * 2);
    __hip_bfloat16* Wf2 = (__hip_bfloat16*)alloc((size_t)EE * FF * 2);
    __hip_bfloat16* hs2b= (__hip_bfloat16*)alloc((size_t)MQ * EE * 2);
    __hip_bfloat16* h1b = (__hip_bfloat16*)alloc((size_t)MQ * FF * 2);
    __hip_bfloat16* attO  = (__hip_bfloat16*)alloc((size_t)MQ * EE * 2);
    __hip_bfloat16* attO2 = (__hip_bfloat16*)alloc((size_t)MQ * EE * 2);
    float* xproj = (float*)alloc((size_t)MQ * EE * 4);
    float* hs1   = (float*)alloc((size_t)MQ * EE * 4);
    float* xpro2 = (float*)alloc((size_t)MQ * EE * 4);
    float* hs2   = (float*)alloc((size_t)MQ * EE * 4);
    float* xffn  = (float*)alloc((size_t)MQ * EE * 4);

    const float qscale = 0.17677669529663687f;
    dim3 blk(256);

    cvt_all<<<dim3(1536), blk, 0, stream>>>(
        ca_wq, ca_wk, ca_wv, ca_wo, sa_wq, sa_wk, sa_wv, sa_wo, fc1_w, fc2_w,
        (unsigned short*)Wq1, (unsigned short*)Wkb, (unsigned short*)Wvb,
        (unsigned short*)Wo1, (unsigned short*)Wq2, (unsigned short*)Wk2,
        (unsigned short*)Wv2, (unsigned short*)Wo2, (unsigned short*)Wf1,
        (unsigned short*)Wf2);

    // ---- cross-attention ----
    mfma_gemm2<1,1,0,1,0><<<dim3(MQ/32, 2), dim3(128), 0, stream>>>(hs, qp, Wq1, ca_bq, Qc, EE, EE, qscale);
    proj_kv<<<dim3(MK/32), blk, 0, stream>>>(enc, ep, Wkb, ca_bk, Wvb, ca_bv, Kc, Vt);
    flash_mfma<<<dim3(BB*HH*2), dim3(256), 0, stream>>>(Qc, Kc, Vt, mask, attO, SS, SS);
    mfma_gemm2<0,0,1,0,0><<<dim3(MQ/32, 2), dim3(128), 0, stream>>>(attO, nullptr, Wo1, ca_bo, xproj, EE, EE, 1.f);
    ln_kernel<1,0,0><<<dim3(MQ), blk, 0, stream>>>(hs, xproj, ln1_g, ln1_b, hs1, nullptr);

    // ---- self-attention ----
    qkv_sa<<<dim3(MQ/32, 2), dim3(128), 0, stream>>>(hs1, qp, Wq2, sa_bq, Wk2, sa_bk, Wv2, sa_bv,
                                                     Qs, Ks2, Vt2, SVT2, qscale);
    flash_mfma<<<dim3(BB*HH*2), dim3(256), 0, stream>>>(Qs, Ks2, Vt2, nullptr, attO2, TQ, SVT2);
    mfma_gemm2<0,0,1,0,0><<<dim3(MQ/32, 2), dim3(128), 0, stream>>>(attO2, nullptr, Wo2, sa_bo, xpro2, EE, EE, 1.f);
    ln_kernel<0,0,1><<<dim3(MQ), blk, 0, stream>>>(hs1, xpro2, ln2_g, ln2_b, hs2, hs2b);

    // ---- FFN ----
    mfma_gemm2<0,0,1,1,1><<<dim3(MQ/32, FF/128), dim3(128), 0, stream>>>(hs2b, nullptr, Wf1, fc1_b, h1b, FF, EE, 1.f);
    mfma_gemm2<0,0,1,0,0><<<dim3(MQ/32, 2), dim3(128), 0, stream>>>(h1b, nullptr, Wf2, fc2_b, xffn, EE, FF, 1.f);
    ln_kernel<0,1,0><<<dim3(MQ), blk, 0, stream>>>(hs2, xffn, ln3_g, ln3_b, (float*)d_out, nullptr);

    (void)in_sizes; (void)n_in; (void)out_size; (void)ws_size;
}

// Round 10
// 390.466 us; speedup vs baseline: 1.1095x; 1.1095x over previous
//
#include <hip/hip_runtime.h>
#include <hip/hip_bf16.h>
#include <math.h>

#define TQ 100
#define SS 4096
#define BB 32
#define EE 256
#define HH 8
#define FF 2048
#define DHH 32
#define LNEPS 1e-5f

typedef __attribute__((ext_vector_type(8))) short bf16x8;
typedef __attribute__((ext_vector_type(4))) short bf16x4;
typedef __attribute__((ext_vector_type(4))) float f32x4;

__device__ inline unsigned short f2bfu(float f) {
    __hip_bfloat16 h = __float2bfloat16(f);
    return *reinterpret_cast<unsigned short*>(&h);
}

#define PBM 64
#define PBK 32
#define PLDP 40
#define TLP 268

// ---------------- fused weight fp32->bf16 convert (10 segments, 1 launch) ----------------
__global__ __launch_bounds__(256)
void cvt_all(const float* s0, const float* s1, const float* s2, const float* s3,
             const float* s4, const float* s5, const float* s6, const float* s7,
             const float* s8, const float* s9,
             unsigned short* d0, unsigned short* d1, unsigned short* d2, unsigned short* d3,
             unsigned short* d4, unsigned short* d5, unsigned short* d6, unsigned short* d7,
             unsigned short* d8, unsigned short* d9)
{
    const int bi = blockIdx.x;
    const float* s; unsigned short* d; int base;
    if (bi < 512) {
        const int seg = bi >> 6;
        base = (bi & 63) * 1024;
        switch (seg) {
            case 0: s = s0; d = d0; break;
            case 1: s = s1; d = d1; break;
            case 2: s = s2; d = d2; break;
            case 3: s = s3; d = d3; break;
            case 4: s = s4; d = d4; break;
            case 5: s = s5; d = d5; break;
            case 6: s = s6; d = d6; break;
            default: s = s7; d = d7; break;
        }
    } else {
        const int r = bi - 512;
        base = (r & 511) * 1024;
        if (r >> 9) { s = s9; d = d9; } else { s = s8; d = d8; }
    }
    const int i = base + threadIdx.x * 4;
    float4 v = *(const float4*)(s + i);
    ushort4 ov;
    ov.x = f2bfu(v.x); ov.y = f2bfu(v.y); ov.z = f2bfu(v.z); ov.w = f2bfu(v.w);
    *(ushort4*)(d + i) = ov;
}

// ---------------- fused K + V^T projection, 8 waves, wave-specialized K|V (R7 version) ----------------
__global__ __launch_bounds__(512, 4)
void proj_kv(const float* __restrict__ enc, const float* __restrict__ ep,
             const __hip_bfloat16* __restrict__ Wk, const float* __restrict__ bk,
             const __hip_bfloat16* __restrict__ Wv, const float* __restrict__ bv,
             __hip_bfloat16* __restrict__ Kout, __hip_bfloat16* __restrict__ Vtout)
{
    __shared__ short Akv[PBM][PLDP];
    __shared__ short Av[PBM][PLDP];
    __shared__ short BkRaw[256 * PLDP];
    __shared__ short BvRaw[256 * PLDP];
    short (*Bk)[PLDP] = (short(*)[PLDP])BkRaw;
    short (*Bv)[PLDP] = (short(*)[PLDP])BvRaw;
    short (*tk)[TLP] = (short(*)[TLP])BkRaw;
    short (*tv)[TLP] = (short(*)[TLP])BvRaw;

    const int tid = threadIdx.x;
    const int m0 = blockIdx.x * PBM;
    const int b = m0 >> 12;
    const int s0 = m0 & (SS - 1);

    const int arr = tid >> 3;
    const int arc = (tid & 7) << 2;
    const long long abase = ((long long)(s0 + arr) * BB + b) * EE + arc;
    const int wr = tid >> 1;
    const int wc = (tid & 1) << 4;
    const long long wbase = (long long)wr * EE + wc;

    const int w = tid >> 6, l = tid & 63;
    const int mat = w >> 2;
    const int wm0 = (w & 1) * 32;
    const int wn0 = ((w >> 1) & 1) * 128;
    const int lr16 = l & 15, lk8 = (l >> 4) * 8;

    f32x4 acc[2][8] = {};

    float4 a0 = *(const float4*)(enc + abase);
    float4 e0 = *(const float4*)(ep + abase);

    for (int k0 = 0; k0 < EE; k0 += PBK) {
        bf16x8 wk8a = *(const bf16x8*)(Wk + wbase + k0);
        bf16x8 wk8b = *(const bf16x8*)(Wk + wbase + k0 + 8);
        bf16x8 wv8a = *(const bf16x8*)(Wv + wbase + k0);
        bf16x8 wv8b = *(const bf16x8*)(Wv + wbase + k0 + 8);

        bf16x4 pv, pkv;
        pv[0] = (short)f2bfu(a0.x); pv[1] = (short)f2bfu(a0.y);
        pv[2] = (short)f2bfu(a0.z); pv[3] = (short)f2bfu(a0.w);
        pkv[0] = (short)f2bfu(a0.x + e0.x); pkv[1] = (short)f2bfu(a0.y + e0.y);
        pkv[2] = (short)f2bfu(a0.z + e0.z); pkv[3] = (short)f2bfu(a0.w + e0.w);

        __syncthreads();
        *(bf16x4*)&Akv[arr][arc] = pkv;
        *(bf16x4*)&Av[arr][arc]  = pv;
        *(bf16x8*)&Bk[wr][wc]     = wk8a;
        *(bf16x8*)&Bk[wr][wc + 8] = wk8b;
        *(bf16x8*)&Bv[wr][wc]     = wv8a;
        *(bf16x8*)&Bv[wr][wc + 8] = wv8b;
        __syncthreads();

        if (k0 + PBK < EE) {
            a0 = *(const float4*)(enc + abase + k0 + PBK);
            e0 = *(const float4*)(ep + abase + k0 + PBK);
        }

        const short (*Am)[PLDP] = mat ? Av : Akv;
        const short (*Bm)[PLDP] = mat ? Bv : Bk;
        bf16x8 af0 = *(const bf16x8*)&Am[wm0 + lr16][lk8];
        bf16x8 af1 = *(const bf16x8*)&Am[wm0 + 16 + lr16][lk8];
        #pragma unroll
        for (int j = 0; j < 8; ++j) {
            bf16x8 b8 = *(const bf16x8*)&Bm[wn0 + j * 16 + lr16][lk8];
            acc[0][j] = __builtin_amdgcn_mfma_f32_16x16x32_bf16(af0, b8, acc[0][j], 0, 0, 0);
            acc[1][j] = __builtin_amdgcn_mfma_f32_16x16x32_bf16(af1, b8, acc[1][j], 0, 0, 0);
        }
    }

    const float* bias = mat ? bv : bk;
    const int q4 = (l >> 4) * 4;
    #pragma unroll
    for (int h = 0; h < 2; ++h) {
        __syncthreads();
        if (wm0 == h * 32) {
            short (*tile)[TLP] = mat ? tv : tk;
            #pragma unroll
            for (int i = 0; i < 2; ++i) {
                #pragma unroll
                for (int j = 0; j < 8; ++j) {
                    const int n = wn0 + j * 16 + lr16;
                    const float bi = bias[n];
                    #pragma unroll
                    for (int r = 0; r < 4; ++r)
                        tile[i * 16 + q4 + r][n] = (short)f2bfu(acc[i][j][r] + bi);
                }
            }
        }
        __syncthreads();
        #pragma unroll
        for (int it = 0; it < 4; ++it) {
            const int r2 = w * 4 + it;
            ushort4 v = *(const ushort4*)&tk[r2][l * 4];
            *(ushort4*)(Kout + (long long)(m0 + h * 32 + r2) * EE + l * 4) = v;
        }
        #pragma unroll
        for (int nn = 0; nn < 16; ++nn) {
            const int n = w * 32 + nn * 2 + (l >> 5);
            const int s = l & 31;
            unsigned short v = (unsigned short)tv[s][n];
            *((unsigned short*)Vtout + (long long)(b * EE + n) * SS + s0 + h * 32 + s) = v;
        }
    }
}

// ---------------- small MFMA GEMM: 32m x 128n tile, 128 threads ----------------
template<int A1G, int A2Q, int A1BF, int OBF, int RELU>
__global__ __launch_bounds__(128)
void mfma_gemm2(const void* __restrict__ A1v, const float* __restrict__ A2,
                const __hip_bfloat16* __restrict__ Wb, const float* __restrict__ bias,
                void* __restrict__ outv, int N, int K, float scale)
{
    __shared__ short As[32][PLDP];
    __shared__ short Bs[128][PLDP];
    const int tid = threadIdx.x;
    const int m0 = blockIdx.x * 32;
    const int n0 = blockIdx.y * 128;
    const int rr = tid >> 2;
    const int rc = (tid & 3) << 3;
    const int row = m0 + rr;

    long long a2row = 0;
    if (A1G || A2Q) {
        int bq = row / TQ, tq = row - bq * TQ;
        a2row = ((long long)(tq * BB + bq)) * EE;
    }
    const long long a1row = A1G ? a2row : (long long)row * K;

    const int wv = tid >> 6, l = tid & 63;
    const int wm0 = wv * 16;
    const int lr16 = l & 15, lk8 = (l >> 4) * 8;

    f32x4 acc[8] = {};

    for (int k0 = 0; k0 < K; k0 += PBK) {
        bf16x8 apack;
        if (A1BF) {
            apack = *(const bf16x8*)((const __hip_bfloat16*)A1v + a1row + k0 + rc);
        } else {
            const float* A1 = (const float*)A1v;
            float4 a0 = *(const float4*)(A1 + a1row + k0 + rc);
            float4 a1 = *(const float4*)(A1 + a1row + k0 + rc + 4);
            if (A2Q) {
                float4 e0 = *(const float4*)(A2 + a2row + k0 + rc);
                float4 e1 = *(const float4*)(A2 + a2row + k0 + rc + 4);
                a0.x += e0.x; a0.y += e0.y; a0.z += e0.z; a0.w += e0.w;
                a1.x += e1.x; a1.y += e1.y; a1.z += e1.z; a1.w += e1.w;
            }
            apack[0] = (short)f2bfu(a0.x); apack[1] = (short)f2bfu(a0.y);
            apack[2] = (short)f2bfu(a0.z); apack[3] = (short)f2bfu(a0.w);
            apack[4] = (short)f2bfu(a1.x); apack[5] = (short)f2bfu(a1.y);
            apack[6] = (short)f2bfu(a1.z); apack[7] = (short)f2bfu(a1.w);
        }

        bf16x8 wreg[4];
        #pragma unroll
        for (int it = 0; it < 4; ++it)
            wreg[it] = *(const bf16x8*)(Wb + (long long)(n0 + rr + it * 32) * K + k0 + rc);

        __syncthreads();
        *(bf16x8*)&As[rr][rc] = apack;
        #pragma unroll
        for (int it = 0; it < 4; ++it)
            *(bf16x8*)&Bs[rr + it * 32][rc] = wreg[it];
        __syncthreads();

        bf16x8 af = *(const bf16x8*)&As[wm0 + lr16][lk8];
        #pragma unroll
        for (int j = 0; j < 8; ++j) {
            bf16x8 bfr = *(const bf16x8*)&Bs[j * 16 + lr16][lk8];
            acc[j] = __builtin_amdgcn_mfma_f32_16x16x32_bf16(af, bfr, acc[j], 0, 0, 0);
        }
    }

    const int q4 = (l >> 4) * 4;
    #pragma unroll
    for (int j = 0; j < 8; ++j) {
        const int n = n0 + j * 16 + lr16;
        const float bi = bias[n];
        #pragma unroll
        for (int r = 0; r < 4; ++r) {
            float v = (acc[j][r] + bi) * scale;
            if (RELU) v = fmaxf(v, 0.f);
            const long long oidx = (long long)(m0 + wm0 + q4 + r) * N + n;
            if (OBF) ((__hip_bfloat16*)outv)[oidx] = __float2bfloat16(v);
            else     ((float*)outv)[oidx] = v;
        }
    }
}

// ---------------- GEMM (N=256) + fused residual + LayerNorm ----------------
// C = A@W^T + bias; out = LN(res + C)*gam + bet.
// A bf16 [M][K]. GRES: res is seq-first gathered. OUT_T: out seq-first. OUT_BF: also bf16 copy.
template<int GRES, int OUT_T, int OUT_BF>
__global__ __launch_bounds__(256)
void gemm_ln(const __hip_bfloat16* __restrict__ A,
             const __hip_bfloat16* __restrict__ Wb, const float* __restrict__ bias,
             const float* __restrict__ res,
             const float* __restrict__ gam, const float* __restrict__ bet,
             float* __restrict__ out, __hip_bfloat16* __restrict__ outb, int K)
{
    __shared__ __align__(16) char raw[32 * 260 * 4];   // 33.3 KB union
    short (*As)[PLDP] = (short(*)[PLDP])raw;            // 32 x 40 (2.5 KB)
    short (*Bs)[PLDP] = (short(*)[PLDP])(raw + 2560);   // 256 x 40 (20 KB)
    float (*tile)[260] = (float(*)[260])raw;            // 32 x 260 fp32

    const int tid = threadIdx.x;
    const int m0 = blockIdx.x * 32;
    const int w = tid >> 6, l = tid & 63;
    const int wn0 = w * 64;
    const int lr16 = l & 15, lk8 = (l >> 4) * 8;
    const int arr = tid >> 3, arc = (tid & 7) << 2;
    const int rr = tid >> 2, rc = (tid & 3) << 3;

    f32x4 acc[2][4] = {};

    for (int k0 = 0; k0 < K; k0 += PBK) {
        bf16x4 ap = *(const bf16x4*)(A + (long long)(m0 + arr) * K + k0 + arc);
        bf16x8 wreg[4];
        #pragma unroll
        for (int it = 0; it < 4; ++it)
            wreg[it] = *(const bf16x8*)(Wb + (long long)(rr + it * 64) * K + k0 + rc);
        __syncthreads();
        *(bf16x4*)&As[arr][arc] = ap;
        #pragma unroll
        for (int it = 0; it < 4; ++it)
            *(bf16x8*)&Bs[rr + it * 64][rc] = wreg[it];
        __syncthreads();
        bf16x8 af0 = *(const bf16x8*)&As[lr16][lk8];
        bf16x8 af1 = *(const bf16x8*)&As[16 + lr16][lk8];
        #pragma unroll
        for (int j = 0; j < 4; ++j) {
            bf16x8 bfr = *(const bf16x8*)&Bs[wn0 + j * 16 + lr16][lk8];
            acc[0][j] = __builtin_amdgcn_mfma_f32_16x16x32_bf16(af0, bfr, acc[0][j], 0, 0, 0);
            acc[1][j] = __builtin_amdgcn_mfma_f32_16x16x32_bf16(af1, bfr, acc[1][j], 0, 0, 0);
        }
    }

    __syncthreads();   // done with As/Bs; reuse raw as fp32 tile
    const int q4 = (l >> 4) * 4;
    #pragma unroll
    for (int i = 0; i < 2; ++i)
        #pragma unroll
        for (int j = 0; j < 4; ++j) {
            const int n = wn0 + j * 16 + lr16;
            const float bi = bias[n];
            #pragma unroll
            for (int r = 0; r < 4; ++r)
                tile[i * 16 + q4 + r][n] = acc[i][j][r] + bi;
        }
    __syncthreads();

    // LN: row = tid>>3 (32 rows), 8 lanes/row, 32 cols/lane
    const int r = tid >> 3, c0 = (tid & 7) * 32;
    const int m = m0 + r;
    const int bq = m / TQ, tq = m - bq * TQ;
    const long long roff = GRES ? ((long long)(tq * BB + bq)) * EE : (long long)m * EE;
    float4 v[8];
    float s = 0.f;
    #pragma unroll
    for (int i = 0; i < 8; ++i) {
        float4 tv = *(const float4*)&tile[r][c0 + i * 4];
        float4 rv = *(const float4*)(res + roff + c0 + i * 4);
        v[i].x = tv.x + rv.x; v[i].y = tv.y + rv.y;
        v[i].z = tv.z + rv.z; v[i].w = tv.w + rv.w;
        s += v[i].x + v[i].y + v[i].z + v[i].w;
    }
    s += __shfl_xor(s, 1); s += __shfl_xor(s, 2); s += __shfl_xor(s, 4);
    const float mu = s * (1.0f / EE);
    float s2 = 0.f;
    #pragma unroll
    for (int i = 0; i < 8; ++i) {
        float dx = v[i].x - mu, dy = v[i].y - mu, dz = v[i].z - mu, dw = v[i].w - mu;
        s2 += dx * dx + dy * dy + dz * dz + dw * dw;
    }
    s2 += __shfl_xor(s2, 1); s2 += __shfl_xor(s2, 2); s2 += __shfl_xor(s2, 4);
    const float rs = rsqrtf(s2 * (1.0f / EE) + LNEPS);
    const long long ooff = OUT_T ? ((long long)(tq * BB + bq)) * EE : (long long)m * EE;
    #pragma unroll
    for (int i = 0; i < 8; ++i) {
        const int c = c0 + i * 4;
        float4 g = *(const float4*)(gam + c);
        float4 be = *(const float4*)(bet + c);
        float4 o;
        o.x = (v[i].x - mu) * rs * g.x + be.x;
        o.y = (v[i].y - mu) * rs * g.y + be.y;
        o.z = (v[i].z - mu) * rs * g.z + be.z;
        o.w = (v[i].w - mu) * rs * g.w + be.w;
        *(float4*)(out + ooff + c) = o;
        if (OUT_BF) {
            ushort4 ob;
            ob.x = f2bfu(o.x); ob.y = f2bfu(o.y); ob.z = f2bfu(o.z); ob.w = f2bfu(o.w);
            *(ushort4*)((unsigned short*)outb + (long long)m * EE + c) = ob;
        }
    }
}

// ---------------- fused SA QKV projection ----------------
__global__ __launch_bounds__(128)
void qkv_sa(const float* __restrict__ hs1, const float* __restrict__ qp,
            const __hip_bfloat16* __restrict__ Wq, const float* __restrict__ bq,
            const __hip_bfloat16* __restrict__ Wk, const float* __restrict__ bk,
            const __hip_bfloat16* __restrict__ Wv, const float* __restrict__ bv,
            __hip_bfloat16* __restrict__ Qs, __hip_bfloat16* __restrict__ Ks,
            __hip_bfloat16* __restrict__ Vt, int SVT, float qscale)
{
    __shared__ short Aq[32][PLDP];
    __shared__ short Av[32][PLDP];
    __shared__ short Bq[128][PLDP];
    __shared__ short Bk[128][PLDP];
    __shared__ short Bv[128][PLDP];
    const int tid = threadIdx.x;
    const int m0 = blockIdx.x * 32;
    const int n0 = blockIdx.y * 128;
    const int rr = tid >> 2;
    const int rc = (tid & 3) << 3;
    const int row = m0 + rr;
    const int bq_ = row / TQ, tq = row - bq_ * TQ;
    const long long a1row = (long long)row * EE;
    const long long a2row = ((long long)(tq * BB + bq_)) * EE;

    const int wv = tid >> 6, l = tid & 63;
    const int wm0 = wv * 16;
    const int lr16 = l & 15, lk8 = (l >> 4) * 8;

    f32x4 aq[8] = {}, ak[8] = {}, av[8] = {};

    for (int k0 = 0; k0 < EE; k0 += PBK) {
        float4 a0 = *(const float4*)(hs1 + a1row + k0 + rc);
        float4 a1 = *(const float4*)(hs1 + a1row + k0 + rc + 4);
        float4 e0 = *(const float4*)(qp + a2row + k0 + rc);
        float4 e1 = *(const float4*)(qp + a2row + k0 + rc + 4);
        bf16x8 pq, pv;
        pv[0] = (short)f2bfu(a0.x); pv[1] = (short)f2bfu(a0.y);
        pv[2] = (short)f2bfu(a0.z); pv[3] = (short)f2bfu(a0.w);
        pv[4] = (short)f2bfu(a1.x); pv[5] = (short)f2bfu(a1.y);
        pv[6] = (short)f2bfu(a1.z); pv[7] = (short)f2bfu(a1.w);
        pq[0] = (short)f2bfu(a0.x + e0.x); pq[1] = (short)f2bfu(a0.y + e0.y);
        pq[2] = (short)f2bfu(a0.z + e0.z); pq[3] = (short)f2bfu(a0.w + e0.w);
        pq[4] = (short)f2bfu(a1.x + e1.x); pq[5] = (short)f2bfu(a1.y + e1.y);
        pq[6] = (short)f2bfu(a1.z + e1.z); pq[7] = (short)f2bfu(a1.w + e1.w);

        bf16x8 wq8[4], wk8[4], wv8[4];
        #pragma unroll
        for (int it = 0; it < 4; ++it) {
            const long long wr = (long long)(n0 + rr + it * 32) * EE + k0 + rc;
            wq8[it] = *(const bf16x8*)(Wq + wr);
            wk8[it] = *(const bf16x8*)(Wk + wr);
            wv8[it] = *(const bf16x8*)(Wv + wr);
        }

        __syncthreads();
        *(bf16x8*)&Aq[rr][rc] = pq;
        *(bf16x8*)&Av[rr][rc] = pv;
        #pragma unroll
        for (int it = 0; it < 4; ++it) {
            *(bf16x8*)&Bq[rr + it * 32][rc] = wq8[it];
            *(bf16x8*)&Bk[rr + it * 32][rc] = wk8[it];
            *(bf16x8*)&Bv[rr + it * 32][rc] = wv8[it];
        }
        __syncthreads();

        bf16x8 afq = *(const bf16x8*)&Aq[wm0 + lr16][lk8];
        bf16x8 afv = *(const bf16x8*)&Av[wm0 + lr16][lk8];
        #pragma unroll
        for (int j = 0; j < 8; ++j) {
            bf16x8 b1 = *(const bf16x8*)&Bq[j * 16 + lr16][lk8];
            bf16x8 b2 = *(const bf16x8*)&Bk[j * 16 + lr16][lk8];
            bf16x8 b3 = *(const bf16x8*)&Bv[j * 16 + lr16][lk8];
            aq[j] = __builtin_amdgcn_mfma_f32_16x16x32_bf16(afq, b1, aq[j], 0, 0, 0);
            ak[j] = __builtin_amdgcn_mfma_f32_16x16x32_bf16(afq, b2, ak[j], 0, 0, 0);
            av[j] = __builtin_amdgcn_mfma_f32_16x16x32_bf16(afv, b3, av[j], 0, 0, 0);
        }
    }

    const int q4 = (l >> 4) * 4;
    #pragma unroll
    for (int j = 0; j < 8; ++j) {
        const int n = n0 + j * 16 + lr16;
        const float b1 = bq[n], b2 = bk[n], b3 = bv[n];
        #pragma unroll
        for (int r = 0; r < 4; ++r) {
            const int m = m0 + wm0 + q4 + r;
            Qs[(long long)m * EE + n] = __float2bfloat16((aq[j][r] + b1) * qscale);
            Ks[(long long)m * EE + n] = __float2bfloat16(ak[j][r] + b2);
            const int bb = m / TQ, tt = m - bb * TQ;
            Vt[(long long)(bb * EE + n) * SVT + tt] = __float2bfloat16(av[j][r] + b3);
        }
    }
}

// ---------------- MFMA flash attention: 4 waves, 64 q/block, XCD-chunked swizzle ----------------
#define KVB 32
#define LDP 40

__global__ __launch_bounds__(256, 2)
void flash_mfma(const __hip_bfloat16* __restrict__ Qg,
                const __hip_bfloat16* __restrict__ Kg,
                const __hip_bfloat16* __restrict__ Vtg,
                const float* __restrict__ mask,
                __hip_bfloat16* __restrict__ O,
                int Skv, int SVT)
{
    __shared__ short Ks[2][KVB][LDP];
    __shared__ short Vs[2][KVB][LDP];
    const int tid = threadIdx.x;
    const int l = tid & 63;
    const int g = l >> 4, q16 = l & 15;
    const int chunk = gridDim.x >> 3;
    const int logical = (blockIdx.x & 7) * chunk + (blockIdx.x >> 3);
    const int qb = logical & 1;
    const int bh = logical >> 1;
    const int h = bh & (HH - 1), b = bh >> 3;
    const int q0 = qb * 64 + (tid >> 6) * 16;

    int qc = q0 + q16; if (qc >= TQ) qc = TQ - 1;
    const bf16x8 qfrag = *(const bf16x8*)(Qg + ((long long)(b * TQ + qc)) * EE + h * DHH + g * 8);

    const int srow = tid >> 3;
    const int sseg = (tid & 7) * 4;
    const long long kbase = ((long long)b * Skv) * EE + h * DHH;
    const long long vbase = ((long long)(b * EE + h * DHH)) * SVT;
    const float* mrowp = mask ? mask + ((long long)bh * TQ + qc) * Skv : nullptr;

    f32x4 oacc[2] = {{0.f,0.f,0.f,0.f},{0.f,0.f,0.f,0.f}};
    float mrun = -1e30f, lrun = 0.f;
    const f32x4 zero = {0.f,0.f,0.f,0.f};

    int s_ld = srow; if (s_ld >= Skv) s_ld = Skv - 1;
    bf16x4 kreg = *(const bf16x4*)(Kg + kbase + (long long)s_ld * EE + sseg);
    bf16x4 vreg = *(const bf16x4*)(Vtg + vbase + (long long)srow * SVT + sseg);
    float4 mcur0, mcur1;
    if (mrowp) {
        mcur0 = *(const float4*)(mrowp + g * 4);
        mcur1 = *(const float4*)(mrowp + 16 + g * 4);
    }

    const int nround = (Skv + KVB - 1) / KVB;
    for (int r = 0; r < nround; ++r) {
        const int buf = r & 1;
        *(bf16x4*)&Ks[buf][srow][sseg] = kreg;
        *(bf16x4*)&Vs[buf][srow][sseg] = vreg;
        float4 mnx0, mnx1;
        if (r + 1 < nround) {
            int sn = (r + 1) * KVB + srow; if (sn >= Skv) sn = Skv - 1;
            kreg = *(const bf16x4*)(Kg + kbase + (long long)sn * EE + sseg);
            vreg = *(const bf16x4*)(Vtg + vbase + (long long)srow * SVT + (r + 1) * KVB + sseg);
            if (mrowp) {
                mnx0 = *(const float4*)(mrowp + (r + 1) * KVB + g * 4);
                mnx1 = *(const float4*)(mrowp + (r + 1) * KVB + 16 + g * 4);
            }
        }
        __syncthreads();

        const int s0 = r * KVB;
        f32x4 sT[2];
        #pragma unroll
        for (int t = 0; t < 2; ++t) {
            bf16x8 kf = *(const bf16x8*)&Ks[buf][t * 16 + q16][g * 8];
            sT[t] = __builtin_amdgcn_mfma_f32_16x16x32_bf16(kf, qfrag, zero, 0, 0, 0);
        }
        float sc[8];
        if (mrowp) {
            sc[0] = sT[0][0] + mcur0.x; sc[1] = sT[0][1] + mcur0.y;
            sc[2] = sT[0][2] + mcur0.z; sc[3] = sT[0][3] + mcur0.w;
            sc[4] = sT[1][0] + mcur1.x; sc[5] = sT[1][1] + mcur1.y;
            sc[6] = sT[1][2] + mcur1.z; sc[7] = sT[1][3] + mcur1.w;
        } else {
            #pragma unroll
            for (int t = 0; t < 2; ++t)
                #pragma unroll
                for (int rg = 0; rg < 4; ++rg) {
                    int s = s0 + t * 16 + g * 4 + rg;
                    sc[t*4+rg] = (s < Skv) ? sT[t][rg] : -1e30f;
                }
        }
        float tmax = sc[0];
        #pragma unroll
        for (int i = 1; i < 8; ++i) tmax = fmaxf(tmax, sc[i]);
        tmax = fmaxf(tmax, __shfl_xor(tmax, 16));
        tmax = fmaxf(tmax, __shfl_xor(tmax, 32));
        const float mn = fmaxf(mrun, tmax);
        const float corr = __expf(mrun - mn);
        mrun = mn;
        float ps = 0.f;
        bf16x8 pfrag;
        #pragma unroll
        for (int i = 0; i < 8; ++i) {
            float p = __expf(sc[i] - mn);
            ps += p;
            pfrag[i] = (short)f2bfu(p);
        }
        ps += __shfl_xor(ps, 16);
        ps += __shfl_xor(ps, 32);
        lrun = lrun * corr + ps;
        #pragma unroll
        for (int rg = 0; rg < 4; ++rg) {
            float c = __shfl(corr, g * 4 + rg);
            oacc[0][rg] *= c;
            oacc[1][rg] *= c;
        }
        #pragma unroll
        for (int T = 0; T < 2; ++T) {
            bf16x4 v0 = *(const bf16x4*)&Vs[buf][T * 16 + q16][g * 4];
            bf16x4 v1 = *(const bf16x4*)&Vs[buf][T * 16 + q16][16 + g * 4];
            bf16x8 vf;
            vf[0] = v0[0]; vf[1] = v0[1]; vf[2] = v0[2]; vf[3] = v0[3];
            vf[4] = v1[0]; vf[5] = v1[1]; vf[6] = v1[2]; vf[7] = v1[3];
            oacc[T] = __builtin_amdgcn_mfma_f32_16x16x32_bf16(pfrag, vf, oacc[T], 0, 0, 0);
        }
        mcur0 = mnx0; mcur1 = mnx1;
        __syncthreads();
    }

    float linv[4];
    #pragma unroll
    for (int rg = 0; rg < 4; ++rg)
        linv[rg] = 1.f / __shfl(lrun, g * 4 + rg);
    #pragma unroll
    for (int rg = 0; rg < 4; ++rg) {
        const int q = q0 + g * 4 + rg;
        if (q < TQ) {
            __hip_bfloat16* op = O + ((long long)(b * TQ + q)) * EE + h * DHH + q16;
            op[0]  = __float2bfloat16(oacc[0][rg] * linv[rg]);
            op[16] = __float2bfloat16(oacc[1][rg] * linv[rg]);
        }
    }
}

extern "C" void kernel_launch(void* const* d_in, const int* in_sizes, int n_in,
                              void* d_out, int out_size, void* d_ws, size_t ws_size,
                              hipStream_t stream)
{
    const float* hs    = (const float*)d_in[0];
    const float* qp    = (const float*)d_in[1];
    const float* enc   = (const float*)d_in[2];
    const float* ep    = (const float*)d_in[3];
    const float* mask  = (const float*)d_in[4];
    const float* ca_wq = (const float*)d_in[5];  const float* ca_bq = (const float*)d_in[6];
    const float* ca_wk = (const float*)d_in[7];  const float* ca_bk = (const float*)d_in[8];
    const float* ca_wv = (const float*)d_in[9];  const float* ca_bv = (const float*)d_in[10];
    const float* ca_wo = (const float*)d_in[11]; const float* ca_bo = (const float*)d_in[12];
    const float* sa_wq = (const float*)d_in[13]; const float* sa_bq = (const float*)d_in[14];
    const float* sa_wk = (const float*)d_in[15]; const float* sa_bk = (const float*)d_in[16];
    const float* sa_wv = (const float*)d_in[17]; const float* sa_bv = (const float*)d_in[18];
    const float* sa_wo = (const float*)d_in[19]; const float* sa_bo = (const float*)d_in[20];
    const float* ln1_g = (const float*)d_in[21]; const float* ln1_b = (const float*)d_in[22];
    const float* ln2_g = (const float*)d_in[23]; const float* ln2_b = (const float*)d_in[24];
    const float* ln3_g = (const float*)d_in[25]; const float* ln3_b = (const float*)d_in[26];
    const float* fc1_w = (const float*)d_in[27]; const float* fc1_b = (const float*)d_in[28];
    const float* fc2_w = (const float*)d_in[29]; const float* fc2_b = (const float*)d_in[30];

    const int MQ = BB * TQ;   // 3200
    const int MK = BB * SS;   // 131072
    const int SVT2 = 128;

    size_t off = 0;
    char* base = (char*)d_ws;
    auto alloc = [&](size_t bytes) -> void* {
        void* p = base + off; off = (off + bytes + 255) & ~(size_t)255; return p;
    };
    __hip_bfloat16* Kc  = (__hip_bfloat16*)alloc((size_t)MK * EE * 2);
    __hip_bfloat16* Vt  = (__hip_bfloat16*)alloc((size_t)BB * EE * SS * 2);
    __hip_bfloat16* Qc  = (__hip_bfloat16*)alloc((size_t)MQ * EE * 2);
    __hip_bfloat16* Qs  = (__hip_bfloat16*)alloc((size_t)MQ * EE * 2);
    __hip_bfloat16* Ks2 = (__hip_bfloat16*)alloc((size_t)MQ * EE * 2);
    __hip_bfloat16* Vt2 = (__hip_bfloat16*)alloc((size_t)BB * EE * SVT2 * 2);
    __hip_bfloat16* Wq1 = (__hip_bfloat16*)alloc((size_t)EE * EE * 2);
    __hip_bfloat16* Wkb = (__hip_bfloat16*)alloc((size_t)EE * EE * 2);
    __hip_bfloat16* Wvb = (__hip_bfloat16*)alloc((size_t)EE * EE * 2);
    __hip_bfloat16* Wo1 = (__hip_bfloat16*)alloc((size_t)EE * EE * 2);
    __hip_bfloat16* Wq2 = (__hip_bfloat16*)alloc((size_t)EE * EE * 2);
    __hip_bfloat16* Wk2 = (__hip_bfloat16*)alloc((size_t)EE * EE * 2);
    __hip_bfloat16* Wv2 = (__hip_bfloat16*)alloc((size_t)EE * EE * 2);
    __hip_bfloat16* Wo2 = (__hip_bfloat16*)alloc((size_t)EE * EE * 2);
    __hip_bfloat16* Wf1 = (__hip_bfloat16*)alloc((size_t)FF * EE * 2);
    __hip_bfloat16* Wf2 = (__hip_bfloat16*)alloc((size_t)EE * FF * 2);
    __hip_bfloat16* hs2b= (__hip_bfloat16*)alloc((size_t)MQ * EE * 2);
    __hip_bfloat16* h1b = (__hip_bfloat16*)alloc((size_t)MQ * FF * 2);
    __hip_bfloat16* attO  = (__hip_bfloat16*)alloc((size_t)MQ * EE * 2);
    __hip_bfloat16* attO2 = (__hip_bfloat16*)alloc((size_t)MQ * EE * 2);
    float* hs1   = (float*)alloc((size_t)MQ * EE * 4);
    float* hs2   = (float*)alloc((size_t)MQ * EE * 4);

    const float qscale = 0.17677669529663687f;
    dim3 blk(256);

    cvt_all<<<dim3(1536), blk, 0, stream>>>(
        ca_wq, ca_wk, ca_wv, ca_wo, sa_wq, sa_wk, sa_wv, sa_wo, fc1_w, fc2_w,
        (unsigned short*)Wq1, (unsigned short*)Wkb, (unsigned short*)Wvb,
        (unsigned short*)Wo1, (unsigned short*)Wq2, (unsigned short*)Wk2,
        (unsigned short*)Wv2, (unsigned short*)Wo2, (unsigned short*)Wf1,
        (unsigned short*)Wf2);

    // ---- cross-attention ----
    mfma_gemm2<1,1,0,1,0><<<dim3(MQ/32, 2), dim3(128), 0, stream>>>(hs, qp, Wq1, ca_bq, Qc, EE, EE, qscale);
    proj_kv<<<dim3(MK/PBM), dim3(512), 0, stream>>>(enc, ep, Wkb, ca_bk, Wvb, ca_bv, Kc, Vt);
    flash_mfma<<<dim3(BB*HH*2), dim3(256), 0, stream>>>(Qc, Kc, Vt, mask, attO, SS, SS);
    gemm_ln<1,0,0><<<dim3(MQ/32), blk, 0, stream>>>(attO, Wo1, ca_bo, hs, ln1_g, ln1_b, hs1, nullptr, EE);

    // ---- self-attention ----
    qkv_sa<<<dim3(MQ/32, 2), dim3(128), 0, stream>>>(hs1, qp, Wq2, sa_bq, Wk2, sa_bk, Wv2, sa_bv,
                                                     Qs, Ks2, Vt2, SVT2, qscale);
    flash_mfma<<<dim3(BB*HH*2), dim3(256), 0, stream>>>(Qs, Ks2, Vt2, nullptr, attO2, TQ, SVT2);
    gemm_ln<0,0,1><<<dim3(MQ/32), blk, 0, stream>>>(attO2, Wo2, sa_bo, hs1, ln2_g, ln2_b, hs2, hs2b, EE);

    // ---- FFN ----
    mfma_gemm2<0,0,1,1,1><<<dim3(MQ/32, FF/128), dim3(128), 0, stream>>>(hs2b, nullptr, Wf1, fc1_b, h1b, FF, EE, 1.f);
    gemm_ln<0,1,0><<<dim3(MQ/32), blk, 0, stream>>>(h1b, Wf2, fc2_b, hs2, ln3_g, ln3_b, (float*)d_out, nullptr, FF);

    (void)in_sizes; (void)n_in; (void)out_size; (void)ws_size;
}

// Round 11
// 366.673 us; speedup vs baseline: 1.1815x; 1.0649x over previous
//
#include <hip/hip_runtime.h>
#include <hip/hip_bf16.h>
#include <math.h>

#define TQ 100
#define SS 4096
#define BB 32
#define EE 256
#define HH 8
#define FF 2048
#define DHH 32
#define LNEPS 1e-5f

typedef __attribute__((ext_vector_type(8))) short bf16x8;
typedef __attribute__((ext_vector_type(4))) short bf16x4;
typedef __attribute__((ext_vector_type(4))) float f32x4;

__device__ inline unsigned short f2bfu(float f) {
    __hip_bfloat16 h = __float2bfloat16(f);
    return *reinterpret_cast<unsigned short*>(&h);
}

#define PBM 64
#define PBK 32
#define PLDP 40
#define TLP 268

// ---------------- fused weight fp32->bf16 convert (10 segments, 1 launch) ----------------
__global__ __launch_bounds__(256)
void cvt_all(const float* s0, const float* s1, const float* s2, const float* s3,
             const float* s4, const float* s5, const float* s6, const float* s7,
             const float* s8, const float* s9,
             unsigned short* d0, unsigned short* d1, unsigned short* d2, unsigned short* d3,
             unsigned short* d4, unsigned short* d5, unsigned short* d6, unsigned short* d7,
             unsigned short* d8, unsigned short* d9)
{
    const int bi = blockIdx.x;
    const float* s; unsigned short* d; int base;
    if (bi < 512) {
        const int seg = bi >> 6;
        base = (bi & 63) * 1024;
        switch (seg) {
            case 0: s = s0; d = d0; break;
            case 1: s = s1; d = d1; break;
            case 2: s = s2; d = d2; break;
            case 3: s = s3; d = d3; break;
            case 4: s = s4; d = d4; break;
            case 5: s = s5; d = d5; break;
            case 6: s = s6; d = d6; break;
            default: s = s7; d = d7; break;
        }
    } else {
        const int r = bi - 512;
        base = (r & 511) * 1024;
        if (r >> 9) { s = s9; d = d9; } else { s = s8; d = d8; }
    }
    const int i = base + threadIdx.x * 4;
    float4 v = *(const float4*)(s + i);
    ushort4 ov;
    ov.x = f2bfu(v.x); ov.y = f2bfu(v.y); ov.z = f2bfu(v.z); ov.w = f2bfu(v.w);
    *(ushort4*)(d + i) = ov;
}

// ---------------- fused K + V^T projection, 8 waves, wave-specialized K|V (R7 best) ----------------
__global__ __launch_bounds__(512, 4)
void proj_kv(const float* __restrict__ enc, const float* __restrict__ ep,
             const __hip_bfloat16* __restrict__ Wk, const float* __restrict__ bk,
             const __hip_bfloat16* __restrict__ Wv, const float* __restrict__ bv,
             __hip_bfloat16* __restrict__ Kout, __hip_bfloat16* __restrict__ Vtout)
{
    __shared__ short Akv[PBM][PLDP];
    __shared__ short Av[PBM][PLDP];
    __shared__ short BkRaw[256 * PLDP];
    __shared__ short BvRaw[256 * PLDP];
    short (*Bk)[PLDP] = (short(*)[PLDP])BkRaw;
    short (*Bv)[PLDP] = (short(*)[PLDP])BvRaw;
    short (*tk)[TLP] = (short(*)[TLP])BkRaw;
    short (*tv)[TLP] = (short(*)[TLP])BvRaw;

    const int tid = threadIdx.x;
    const int m0 = blockIdx.x * PBM;
    const int b = m0 >> 12;
    const int s0 = m0 & (SS - 1);

    const int arr = tid >> 3;
    const int arc = (tid & 7) << 2;
    const long long abase = ((long long)(s0 + arr) * BB + b) * EE + arc;
    const int wr = tid >> 1;
    const int wc = (tid & 1) << 4;
    const long long wbase = (long long)wr * EE + wc;

    const int w = tid >> 6, l = tid & 63;
    const int mat = w >> 2;
    const int wm0 = (w & 1) * 32;
    const int wn0 = ((w >> 1) & 1) * 128;
    const int lr16 = l & 15, lk8 = (l >> 4) * 8;

    f32x4 acc[2][8] = {};

    float4 a0 = *(const float4*)(enc + abase);
    float4 e0 = *(const float4*)(ep + abase);

    for (int k0 = 0; k0 < EE; k0 += PBK) {
        bf16x8 wk8a = *(const bf16x8*)(Wk + wbase + k0);
        bf16x8 wk8b = *(const bf16x8*)(Wk + wbase + k0 + 8);
        bf16x8 wv8a = *(const bf16x8*)(Wv + wbase + k0);
        bf16x8 wv8b = *(const bf16x8*)(Wv + wbase + k0 + 8);

        bf16x4 pv, pkv;
        pv[0] = (short)f2bfu(a0.x); pv[1] = (short)f2bfu(a0.y);
        pv[2] = (short)f2bfu(a0.z); pv[3] = (short)f2bfu(a0.w);
        pkv[0] = (short)f2bfu(a0.x + e0.x); pkv[1] = (short)f2bfu(a0.y + e0.y);
        pkv[2] = (short)f2bfu(a0.z + e0.z); pkv[3] = (short)f2bfu(a0.w + e0.w);

        __syncthreads();
        *(bf16x4*)&Akv[arr][arc] = pkv;
        *(bf16x4*)&Av[arr][arc]  = pv;
        *(bf16x8*)&Bk[wr][wc]     = wk8a;
        *(bf16x8*)&Bk[wr][wc + 8] = wk8b;
        *(bf16x8*)&Bv[wr][wc]     = wv8a;
        *(bf16x8*)&Bv[wr][wc + 8] = wv8b;
        __syncthreads();

        if (k0 + PBK < EE) {
            a0 = *(const float4*)(enc + abase + k0 + PBK);
            e0 = *(const float4*)(ep + abase + k0 + PBK);
        }

        const short (*Am)[PLDP] = mat ? Av : Akv;
        const short (*Bm)[PLDP] = mat ? Bv : Bk;
        bf16x8 af0 = *(const bf16x8*)&Am[wm0 + lr16][lk8];
        bf16x8 af1 = *(const bf16x8*)&Am[wm0 + 16 + lr16][lk8];
        #pragma unroll
        for (int j = 0; j < 8; ++j) {
            bf16x8 b8 = *(const bf16x8*)&Bm[wn0 + j * 16 + lr16][lk8];
            acc[0][j] = __builtin_amdgcn_mfma_f32_16x16x32_bf16(af0, b8, acc[0][j], 0, 0, 0);
            acc[1][j] = __builtin_amdgcn_mfma_f32_16x16x32_bf16(af1, b8, acc[1][j], 0, 0, 0);
        }
    }

    const float* bias = mat ? bv : bk;
    const int q4 = (l >> 4) * 4;
    #pragma unroll
    for (int h = 0; h < 2; ++h) {
        __syncthreads();
        if (wm0 == h * 32) {
            short (*tile)[TLP] = mat ? tv : tk;
            #pragma unroll
            for (int i = 0; i < 2; ++i) {
                #pragma unroll
                for (int j = 0; j < 8; ++j) {
                    const int n = wn0 + j * 16 + lr16;
                    const float bi = bias[n];
                    #pragma unroll
                    for (int r = 0; r < 4; ++r)
                        tile[i * 16 + q4 + r][n] = (short)f2bfu(acc[i][j][r] + bi);
                }
            }
        }
        __syncthreads();
        #pragma unroll
        for (int it = 0; it < 4; ++it) {
            const int r2 = w * 4 + it;
            ushort4 v = *(const ushort4*)&tk[r2][l * 4];
            *(ushort4*)(Kout + (long long)(m0 + h * 32 + r2) * EE + l * 4) = v;
        }
        #pragma unroll
        for (int nn = 0; nn < 16; ++nn) {
            const int n = w * 32 + nn * 2 + (l >> 5);
            const int s = l & 31;
            unsigned short v = (unsigned short)tv[s][n];
            *((unsigned short*)Vtout + (long long)(b * EE + n) * SS + s0 + h * 32 + s) = v;
        }
    }
}

// ---------------- small MFMA GEMM: 32m x 128n tile, 128 threads ----------------
template<int A1G, int A2Q, int A1BF, int OBF, int RELU>
__global__ __launch_bounds__(128)
void mfma_gemm2(const void* __restrict__ A1v, const float* __restrict__ A2,
                const __hip_bfloat16* __restrict__ Wb, const float* __restrict__ bias,
                void* __restrict__ outv, int N, int K, float scale)
{
    __shared__ short As[32][PLDP];
    __shared__ short Bs[128][PLDP];
    const int tid = threadIdx.x;
    const int m0 = blockIdx.x * 32;
    const int n0 = blockIdx.y * 128;
    const int rr = tid >> 2;
    const int rc = (tid & 3) << 3;
    const int row = m0 + rr;

    long long a2row = 0;
    if (A1G || A2Q) {
        int bq = row / TQ, tq = row - bq * TQ;
        a2row = ((long long)(tq * BB + bq)) * EE;
    }
    const long long a1row = A1G ? a2row : (long long)row * K;

    const int wv = tid >> 6, l = tid & 63;
    const int wm0 = wv * 16;
    const int lr16 = l & 15, lk8 = (l >> 4) * 8;

    f32x4 acc[8] = {};

    for (int k0 = 0; k0 < K; k0 += PBK) {
        bf16x8 apack;
        if (A1BF) {
            apack = *(const bf16x8*)((const __hip_bfloat16*)A1v + a1row + k0 + rc);
        } else {
            const float* A1 = (const float*)A1v;
            float4 a0 = *(const float4*)(A1 + a1row + k0 + rc);
            float4 a1 = *(const float4*)(A1 + a1row + k0 + rc + 4);
            if (A2Q) {
                float4 e0 = *(const float4*)(A2 + a2row + k0 + rc);
                float4 e1 = *(const float4*)(A2 + a2row + k0 + rc + 4);
                a0.x += e0.x; a0.y += e0.y; a0.z += e0.z; a0.w += e0.w;
                a1.x += e1.x; a1.y += e1.y; a1.z += e1.z; a1.w += e1.w;
            }
            apack[0] = (short)f2bfu(a0.x); apack[1] = (short)f2bfu(a0.y);
            apack[2] = (short)f2bfu(a0.z); apack[3] = (short)f2bfu(a0.w);
            apack[4] = (short)f2bfu(a1.x); apack[5] = (short)f2bfu(a1.y);
            apack[6] = (short)f2bfu(a1.z); apack[7] = (short)f2bfu(a1.w);
        }

        bf16x8 wreg[4];
        #pragma unroll
        for (int it = 0; it < 4; ++it)
            wreg[it] = *(const bf16x8*)(Wb + (long long)(n0 + rr + it * 32) * K + k0 + rc);

        __syncthreads();
        *(bf16x8*)&As[rr][rc] = apack;
        #pragma unroll
        for (int it = 0; it < 4; ++it)
            *(bf16x8*)&Bs[rr + it * 32][rc] = wreg[it];
        __syncthreads();

        bf16x8 af = *(const bf16x8*)&As[wm0 + lr16][lk8];
        #pragma unroll
        for (int j = 0; j < 8; ++j) {
            bf16x8 bfr = *(const bf16x8*)&Bs[j * 16 + lr16][lk8];
            acc[j] = __builtin_amdgcn_mfma_f32_16x16x32_bf16(af, bfr, acc[j], 0, 0, 0);
        }
    }

    const int q4 = (l >> 4) * 4;
    #pragma unroll
    for (int j = 0; j < 8; ++j) {
        const int n = n0 + j * 16 + lr16;
        const float bi = bias[n];
        #pragma unroll
        for (int r = 0; r < 4; ++r) {
            float v = (acc[j][r] + bi) * scale;
            if (RELU) v = fmaxf(v, 0.f);
            const long long oidx = (long long)(m0 + wm0 + q4 + r) * N + n;
            if (OBF) ((__hip_bfloat16*)outv)[oidx] = __float2bfloat16(v);
            else     ((float*)outv)[oidx] = v;
        }
    }
}

// ---------------- fused SA QKV projection ----------------
__global__ __launch_bounds__(128)
void qkv_sa(const float* __restrict__ hs1, const float* __restrict__ qp,
            const __hip_bfloat16* __restrict__ Wq, const float* __restrict__ bq,
            const __hip_bfloat16* __restrict__ Wk, const float* __restrict__ bk,
            const __hip_bfloat16* __restrict__ Wv, const float* __restrict__ bv,
            __hip_bfloat16* __restrict__ Qs, __hip_bfloat16* __restrict__ Ks,
            __hip_bfloat16* __restrict__ Vt, int SVT, float qscale)
{
    __shared__ short Aq[32][PLDP];
    __shared__ short Av[32][PLDP];
    __shared__ short Bq[128][PLDP];
    __shared__ short Bk[128][PLDP];
    __shared__ short Bv[128][PLDP];
    const int tid = threadIdx.x;
    const int m0 = blockIdx.x * 32;
    const int n0 = blockIdx.y * 128;
    const int rr = tid >> 2;
    const int rc = (tid & 3) << 3;
    const int row = m0 + rr;
    const int bq_ = row / TQ, tq = row - bq_ * TQ;
    const long long a1row = (long long)row * EE;
    const long long a2row = ((long long)(tq * BB + bq_)) * EE;

    const int wv = tid >> 6, l = tid & 63;
    const int wm0 = wv * 16;
    const int lr16 = l & 15, lk8 = (l >> 4) * 8;

    f32x4 aq[8] = {}, ak[8] = {}, av[8] = {};

    for (int k0 = 0; k0 < EE; k0 += PBK) {
        float4 a0 = *(const float4*)(hs1 + a1row + k0 + rc);
        float4 a1 = *(const float4*)(hs1 + a1row + k0 + rc + 4);
        float4 e0 = *(const float4*)(qp + a2row + k0 + rc);
        float4 e1 = *(const float4*)(qp + a2row + k0 + rc + 4);
        bf16x8 pq, pv;
        pv[0] = (short)f2bfu(a0.x); pv[1] = (short)f2bfu(a0.y);
        pv[2] = (short)f2bfu(a0.z); pv[3] = (short)f2bfu(a0.w);
        pv[4] = (short)f2bfu(a1.x); pv[5] = (short)f2bfu(a1.y);
        pv[6] = (short)f2bfu(a1.z); pv[7] = (short)f2bfu(a1.w);
        pq[0] = (short)f2bfu(a0.x + e0.x); pq[1] = (short)f2bfu(a0.y + e0.y);
        pq[2] = (short)f2bfu(a0.z + e0.z); pq[3] = (short)f2bfu(a0.w + e0.w);
        pq[4] = (short)f2bfu(a1.x + e1.x); pq[5] = (short)f2bfu(a1.y + e1.y);
        pq[6] = (short)f2bfu(a1.z + e1.z); pq[7] = (short)f2bfu(a1.w + e1.w);

        bf16x8 wq8[4], wk8[4], wv8[4];
        #pragma unroll
        for (int it = 0; it < 4; ++it) {
            const long long wrx = (long long)(n0 + rr + it * 32) * EE + k0 + rc;
            wq8[it] = *(const bf16x8*)(Wq + wrx);
            wk8[it] = *(const bf16x8*)(Wk + wrx);
            wv8[it] = *(const bf16x8*)(Wv + wrx);
        }

        __syncthreads();
        *(bf16x8*)&Aq[rr][rc] = pq;
        *(bf16x8*)&Av[rr][rc] = pv;
        #pragma unroll
        for (int it = 0; it < 4; ++it) {
            *(bf16x8*)&Bq[rr + it * 32][rc] = wq8[it];
            *(bf16x8*)&Bk[rr + it * 32][rc] = wk8[it];
            *(bf16x8*)&Bv[rr + it * 32][rc] = wv8[it];
        }
        __syncthreads();

        bf16x8 afq = *(const bf16x8*)&Aq[wm0 + lr16][lk8];
        bf16x8 afv = *(const bf16x8*)&Av[wm0 + lr16][lk8];
        #pragma unroll
        for (int j = 0; j < 8; ++j) {
            bf16x8 b1 = *(const bf16x8*)&Bq[j * 16 + lr16][lk8];
            bf16x8 b2 = *(const bf16x8*)&Bk[j * 16 + lr16][lk8];
            bf16x8 b3 = *(const bf16x8*)&Bv[j * 16 + lr16][lk8];
            aq[j] = __builtin_amdgcn_mfma_f32_16x16x32_bf16(afq, b1, aq[j], 0, 0, 0);
            ak[j] = __builtin_amdgcn_mfma_f32_16x16x32_bf16(afq, b2, ak[j], 0, 0, 0);
            av[j] = __builtin_amdgcn_mfma_f32_16x16x32_bf16(afv, b3, av[j], 0, 0, 0);
        }
    }

    const int q4 = (l >> 4) * 4;
    #pragma unroll
    for (int j = 0; j < 8; ++j) {
        const int n = n0 + j * 16 + lr16;
        const float b1 = bq[n], b2 = bk[n], b3 = bv[n];
        #pragma unroll
        for (int r = 0; r < 4; ++r) {
            const int m = m0 + wm0 + q4 + r;
            Qs[(long long)m * EE + n] = __float2bfloat16((aq[j][r] + b1) * qscale);
            Ks[(long long)m * EE + n] = __float2bfloat16(ak[j][r] + b2);
            const int bb = m / TQ, tt = m - bb * TQ;
            Vt[(long long)(bb * EE + n) * SVT + tt] = __float2bfloat16(av[j][r] + b3);
        }
    }
}

// ---------------- MFMA flash attention: 8 waves, 128 q/block, ONE block per (b,h), KVB=64 ----------------
#define KVB 64

__global__ __launch_bounds__(512, 2)
void flash_mfma(const __hip_bfloat16* __restrict__ Qg,
                const __hip_bfloat16* __restrict__ Kg,
                const __hip_bfloat16* __restrict__ Vtg,
                const float* __restrict__ mask,
                __hip_bfloat16* __restrict__ O,
                int Skv, int SVT)
{
    __shared__ short Ks[2][KVB][40];     // rows = s-local, 32 shorts + pad
    __shared__ short Vs[2][DHH][72];     // rows = d, 64 shorts + pad
    const int tid = threadIdx.x;
    const int l = tid & 63;
    const int g = l >> 4, q16 = l & 15;
    const int bh = blockIdx.x;
    const int h = bh & (HH - 1), b = bh >> 3;
    const int q0 = (tid >> 6) * 16;

    int qc = q0 + q16; if (qc >= TQ) qc = TQ - 1;
    const bf16x8 qfrag = *(const bf16x8*)(Qg + ((long long)(b * TQ + qc)) * EE + h * DHH + g * 8);

    const int ksr = tid >> 3;           // 0..63 (s-local)
    const int ksc = (tid & 7) * 4;      // 0..28
    const int vsr = tid >> 4;           // 0..31 (d)
    const int vsc = (tid & 15) * 4;     // 0..60 (s-local)
    const long long kbase = ((long long)b * Skv) * EE + h * DHH;
    const long long vbase = ((long long)(b * EE + h * DHH)) * SVT;
    const float* mrowp = mask ? mask + ((long long)bh * TQ + qc) * Skv : nullptr;

    f32x4 oacc[2] = {{0.f,0.f,0.f,0.f},{0.f,0.f,0.f,0.f}};
    float mrun = -1e30f, lrun = 0.f;
    const f32x4 zero = {0.f,0.f,0.f,0.f};

    int s_ld = ksr; if (s_ld >= Skv) s_ld = Skv - 1;
    bf16x4 kreg = *(const bf16x4*)(Kg + kbase + (long long)s_ld * EE + ksc);
    bf16x4 vreg = *(const bf16x4*)(Vtg + vbase + (long long)vsr * SVT + vsc);
    float4 mcur[4], mnx[4];
    if (mrowp) {
        #pragma unroll
        for (int t = 0; t < 4; ++t) mcur[t] = *(const float4*)(mrowp + t * 16 + g * 4);
    }

    const int nround = (Skv + KVB - 1) / KVB;
    for (int r = 0; r < nround; ++r) {
        const int buf = r & 1;
        *(bf16x4*)&Ks[buf][ksr][ksc] = kreg;
        *(bf16x4*)&Vs[buf][vsr][vsc] = vreg;
        if (r + 1 < nround) {
            int sn = (r + 1) * KVB + ksr; if (sn >= Skv) sn = Skv - 1;
            kreg = *(const bf16x4*)(Kg + kbase + (long long)sn * EE + ksc);
            vreg = *(const bf16x4*)(Vtg + vbase + (long long)vsr * SVT + (r + 1) * KVB + vsc);
            if (mrowp) {
                #pragma unroll
                for (int t = 0; t < 4; ++t)
                    mnx[t] = *(const float4*)(mrowp + (r + 1) * KVB + t * 16 + g * 4);
            }
        }
        __syncthreads();

        const int s0 = r * KVB;
        // S^T = mfma(K, Q): lane holds q = q16, s-slots 16t+4g+rg
        f32x4 sT[4];
        #pragma unroll
        for (int t = 0; t < 4; ++t) {
            bf16x8 kf = *(const bf16x8*)&Ks[buf][t * 16 + q16][g * 8];
            sT[t] = __builtin_amdgcn_mfma_f32_16x16x32_bf16(kf, qfrag, zero, 0, 0, 0);
        }
        float sc[16];
        if (mrowp) {
            #pragma unroll
            for (int t = 0; t < 4; ++t) {
                sc[t*4+0] = sT[t][0] + mcur[t].x; sc[t*4+1] = sT[t][1] + mcur[t].y;
                sc[t*4+2] = sT[t][2] + mcur[t].z; sc[t*4+3] = sT[t][3] + mcur[t].w;
            }
        } else {
            #pragma unroll
            for (int t = 0; t < 4; ++t)
                #pragma unroll
                for (int rg = 0; rg < 4; ++rg) {
                    int s = s0 + t * 16 + g * 4 + rg;
                    sc[t*4+rg] = (s < Skv) ? sT[t][rg] : -1e30f;
                }
        }
        float tmax = sc[0];
        #pragma unroll
        for (int i = 1; i < 16; ++i) tmax = fmaxf(tmax, sc[i]);
        tmax = fmaxf(tmax, __shfl_xor(tmax, 16));
        tmax = fmaxf(tmax, __shfl_xor(tmax, 32));
        const float mn = fmaxf(mrun, tmax);
        const float corr = __expf(mrun - mn);
        mrun = mn;
        float ps = 0.f;
        float pe[16];
        #pragma unroll
        for (int i = 0; i < 16; ++i) {
            pe[i] = __expf(sc[i] - mn);
            ps += pe[i];
        }
        ps += __shfl_xor(ps, 16);
        ps += __shfl_xor(ps, 32);
        lrun = lrun * corr + ps;
        #pragma unroll
        for (int rg = 0; rg < 4; ++rg) {
            float c = __shfl(corr, g * 4 + rg);
            oacc[0][rg] *= c;
            oacc[1][rg] *= c;
        }
        // PV over two 32-wide s-blocks; slot permutation matches between pfrag and vf
        #pragma unroll
        for (int sb = 0; sb < 2; ++sb) {
            bf16x8 pfrag;
            #pragma unroll
            for (int e = 0; e < 4; ++e) {
                pfrag[e]     = (short)f2bfu(pe[(2*sb)*4 + e]);
                pfrag[e + 4] = (short)f2bfu(pe[(2*sb+1)*4 + e]);
            }
            #pragma unroll
            for (int T = 0; T < 2; ++T) {
                bf16x4 v0 = *(const bf16x4*)&Vs[buf][T * 16 + q16][sb * 32 + g * 4];
                bf16x4 v1 = *(const bf16x4*)&Vs[buf][T * 16 + q16][sb * 32 + 16 + g * 4];
                bf16x8 vf;
                vf[0] = v0[0]; vf[1] = v0[1]; vf[2] = v0[2]; vf[3] = v0[3];
                vf[4] = v1[0]; vf[5] = v1[1]; vf[6] = v1[2]; vf[7] = v1[3];
                oacc[T] = __builtin_amdgcn_mfma_f32_16x16x32_bf16(pfrag, vf, oacc[T], 0, 0, 0);
            }
        }
        #pragma unroll
        for (int t = 0; t < 4; ++t) mcur[t] = mnx[t];
        __syncthreads();
    }

    float linv[4];
    #pragma unroll
    for (int rg = 0; rg < 4; ++rg)
        linv[rg] = 1.f / __shfl(lrun, g * 4 + rg);
    #pragma unroll
    for (int rg = 0; rg < 4; ++rg) {
        const int q = q0 + g * 4 + rg;
        if (q < TQ) {
            __hip_bfloat16* op = O + ((long long)(b * TQ + q)) * EE + h * DHH + q16;
            op[0]  = __float2bfloat16(oacc[0][rg] * linv[rg]);
            op[16] = __float2bfloat16(oacc[1][rg] * linv[rg]);
        }
    }
}

// ---------------- LayerNorm ----------------
template<int GATHER_RES, int OUT_T, int OUT_BF>
__global__ __launch_bounds__(256)
void ln_kernel(const float* __restrict__ res, const float* __restrict__ x,
               const float* __restrict__ gam, const float* __restrict__ bet,
               float* __restrict__ out, __hip_bfloat16* __restrict__ outb)
{
    __shared__ float r1[4], r2[4];
    const int m = blockIdx.x;
    const int k = threadIdx.x;
    const int b = m / TQ, t = m - b * TQ;
    const long long roff = GATHER_RES ? ((long long)(t * BB + b)) * EE : (long long)m * EE;
    float v = res[roff + k] + x[(long long)m * EE + k];
    float s = v;
    #pragma unroll
    for (int off = 32; off; off >>= 1) s += __shfl_down(s, off);
    if ((k & 63) == 0) r1[k >> 6] = s;
    __syncthreads();
    const float mu = (r1[0] + r1[1] + r1[2] + r1[3]) * (1.0f / EE);
    const float d = v - mu;
    float s2 = d * d;
    #pragma unroll
    for (int off = 32; off; off >>= 1) s2 += __shfl_down(s2, off);
    if ((k & 63) == 0) r2[k >> 6] = s2;
    __syncthreads();
    const float var = (r2[0] + r2[1] + r2[2] + r2[3]) * (1.0f / EE);
    const float o = d * rsqrtf(var + LNEPS) * gam[k] + bet[k];
    const long long ooff = OUT_T ? ((long long)(t * BB + b)) * EE : (long long)m * EE;
    out[ooff + k] = o;
    if (OUT_BF) outb[(long long)m * EE + k] = __float2bfloat16(o);
}

extern "C" void kernel_launch(void* const* d_in, const int* in_sizes, int n_in,
                              void* d_out, int out_size, void* d_ws, size_t ws_size,
                              hipStream_t stream)
{
    const float* hs    = (const float*)d_in[0];
    const float* qp    = (const float*)d_in[1];
    const float* enc   = (const float*)d_in[2];
    const float* ep    = (const float*)d_in[3];
    const float* mask  = (const float*)d_in[4];
    const float* ca_wq = (const float*)d_in[5];  const float* ca_bq = (const float*)d_in[6];
    const float* ca_wk = (const float*)d_in[7];  const float* ca_bk = (const float*)d_in[8];
    const float* ca_wv = (const float*)d_in[9];  const float* ca_bv = (const float*)d_in[10];
    const float* ca_wo = (const float*)d_in[11]; const float* ca_bo = (const float*)d_in[12];
    const float* sa_wq = (const float*)d_in[13]; const float* sa_bq = (const float*)d_in[14];
    const float* sa_wk = (const float*)d_in[15]; const float* sa_bk = (const float*)d_in[16];
    const float* sa_wv = (const float*)d_in[17]; const float* sa_bv = (const float*)d_in[18];
    const float* sa_wo = (const float*)d_in[19]; const float* sa_bo = (const float*)d_in[20];
    const float* ln1_g = (const float*)d_in[21]; const float* ln1_b = (const float*)d_in[22];
    const float* ln2_g = (const float*)d_in[23]; const float* ln2_b = (const float*)d_in[24];
    const float* ln3_g = (const float*)d_in[25]; const float* ln3_b = (const float*)d_in[26];
    const float* fc1_w = (const float*)d_in[27]; const float* fc1_b = (const float*)d_in[28];
    const float* fc2_w = (const float*)d_in[29]; const float* fc2_b = (const float*)d_in[30];

    const int MQ = BB * TQ;   // 3200
    const int MK = BB * SS;   // 131072
    const int SVT2 = 128;

    size_t off = 0;
    char* base = (char*)d_ws;
    auto alloc = [&](size_t bytes) -> void* {
        void* p = base + off; off = (off + bytes + 255) & ~(size_t)255; return p;
    };
    __hip_bfloat16* Kc  = (__hip_bfloat16*)alloc((size_t)MK * EE * 2);
    __hip_bfloat16* Vt  = (__hip_bfloat16*)alloc((size_t)BB * EE * SS * 2);
    __hip_bfloat16* Qc  = (__hip_bfloat16*)alloc((size_t)MQ * EE * 2);
    __hip_bfloat16* Qs  = (__hip_bfloat16*)alloc((size_t)MQ * EE * 2);
    __hip_bfloat16* Ks2 = (__hip_bfloat16*)alloc((size_t)MQ * EE * 2);
    __hip_bfloat16* Vt2 = (__hip_bfloat16*)alloc((size_t)BB * EE * SVT2 * 2);
    __hip_bfloat16* Wq1 = (__hip_bfloat16*)alloc((size_t)EE * EE * 2);
    __hip_bfloat16* Wkb = (__hip_bfloat16*)alloc((size_t)EE * EE * 2);
    __hip_bfloat16* Wvb = (__hip_bfloat16*)alloc((size_t)EE * EE * 2);
    __hip_bfloat16* Wo1 = (__hip_bfloat16*)alloc((size_t)EE * EE * 2);
    __hip_bfloat16* Wq2 = (__hip_bfloat16*)alloc((size_t)EE * EE * 2);
    __hip_bfloat16* Wk2 = (__hip_bfloat16*)alloc((size_t)EE * EE * 2);
    __hip_bfloat16* Wv2 = (__hip_bfloat16*)alloc((size_t)EE * EE * 2);
    __hip_bfloat16* Wo2 = (__hip_bfloat16*)alloc((size_t)EE * EE * 2);
    __hip_bfloat16* Wf1 = (__hip_bfloat16*)alloc((size_t)FF * EE * 2);
    __hip_bfloat16* Wf2 = (__hip_bfloat16*)alloc((size_t)EE * FF * 2);
    __hip_bfloat16* hs2b= (__hip_bfloat16*)alloc((size_t)MQ * EE * 2);
    __hip_bfloat16* h1b = (__hip_bfloat16*)alloc((size_t)MQ * FF * 2);
    __hip_bfloat16* attO  = (__hip_bfloat16*)alloc((size_t)MQ * EE * 2);
    __hip_bfloat16* attO2 = (__hip_bfloat16*)alloc((size_t)MQ * EE * 2);
    float* xproj = (float*)alloc((size_t)MQ * EE * 4);
    float* hs1   = (float*)alloc((size_t)MQ * EE * 4);
    float* xpro2 = (float*)alloc((size_t)MQ * EE * 4);
    float* hs2   = (float*)alloc((size_t)MQ * EE * 4);
    float* xffn  = (float*)alloc((size_t)MQ * EE * 4);

    const float qscale = 0.17677669529663687f;
    dim3 blk(256);

    cvt_all<<<dim3(1536), blk, 0, stream>>>(
        ca_wq, ca_wk, ca_wv, ca_wo, sa_wq, sa_wk, sa_wv, sa_wo, fc1_w, fc2_w,
        (unsigned short*)Wq1, (unsigned short*)Wkb, (unsigned short*)Wvb,
        (unsigned short*)Wo1, (unsigned short*)Wq2, (unsigned short*)Wk2,
        (unsigned short*)Wv2, (unsigned short*)Wo2, (unsigned short*)Wf1,
        (unsigned short*)Wf2);

    // ---- cross-attention ----
    mfma_gemm2<1,1,0,1,0><<<dim3(MQ/32, 2), dim3(128), 0, stream>>>(hs, qp, Wq1, ca_bq, Qc, EE, EE, qscale);
    proj_kv<<<dim3(MK/PBM), dim3(512), 0, stream>>>(enc, ep, Wkb, ca_bk, Wvb, ca_bv, Kc, Vt);
    flash_mfma<<<dim3(BB*HH), dim3(512), 0, stream>>>(Qc, Kc, Vt, mask, attO, SS, SS);
    mfma_gemm2<0,0,1,0,0><<<dim3(MQ/32, 2), dim3(128), 0, stream>>>(attO, nullptr, Wo1, ca_bo, xproj, EE, EE, 1.f);
    ln_kernel<1,0,0><<<dim3(MQ), blk, 0, stream>>>(hs, xproj, ln1_g, ln1_b, hs1, nullptr);

    // ---- self-attention ----
    qkv_sa<<<dim3(MQ/32, 2), dim3(128), 0, stream>>>(hs1, qp, Wq2, sa_bq, Wk2, sa_bk, Wv2, sa_bv,
                                                     Qs, Ks2, Vt2, SVT2, qscale);
    flash_mfma<<<dim3(BB*HH), dim3(512), 0, stream>>>(Qs, Ks2, Vt2, nullptr, attO2, TQ, SVT2);
    mfma_gemm2<0,0,1,0,0><<<dim3(MQ/32, 2), dim3(128), 0, stream>>>(attO2, nullptr, Wo2, sa_bo, xpro2, EE, EE, 1.f);
    ln_kernel<0,0,1><<<dim3(MQ), blk, 0, stream>>>(hs1, xpro2, ln2_g, ln2_b, hs2, hs2b);

    // ---- FFN ----
    mfma_gemm2<0,0,1,1,1><<<dim3(MQ/32, FF/128), dim3(128), 0, stream>>>(hs2b, nullptr, Wf1, fc1_b, h1b, FF, EE, 1.f);
    mfma_gemm2<0,0,1,0,0><<<dim3(MQ/32, 2), dim3(128), 0, stream>>>(h1b, nullptr, Wf2, fc2_b, xffn, EE, FF, 1.f);
    ln_kernel<0,1,0><<<dim3(MQ), blk, 0, stream>>>(hs2, xffn, ln3_g, ln3_b, (float*)d_out, nullptr);

    (void)in_sizes; (void)n_in; (void)out_size; (void)ws_size;
}

// Round 12
// 361.217 us; speedup vs baseline: 1.1994x; 1.0151x over previous
//
#include <hip/hip_runtime.h>
#include <hip/hip_bf16.h>
#include <math.h>

#define TQ 100
#define SS 4096
#define BB 32
#define EE 256
#define HH 8
#define FF 2048
#define DHH 32
#define LNEPS 1e-5f

typedef __attribute__((ext_vector_type(8))) short bf16x8;
typedef __attribute__((ext_vector_type(4))) short bf16x4;
typedef __attribute__((ext_vector_type(4))) float f32x4;

__device__ inline unsigned short f2bfu(float f) {
    __hip_bfloat16 h = __float2bfloat16(f);
    return *reinterpret_cast<unsigned short*>(&h);
}

#define PBM 64
#define PBK 32
#define PLDP 40
#define TLP 268

// ---------------- fused weight fp32->bf16 convert (10 segments, 1 launch) ----------------
__global__ __launch_bounds__(256)
void cvt_all(const float* s0, const float* s1, const float* s2, const float* s3,
             const float* s4, const float* s5, const float* s6, const float* s7,
             const float* s8, const float* s9,
             unsigned short* d0, unsigned short* d1, unsigned short* d2, unsigned short* d3,
             unsigned short* d4, unsigned short* d5, unsigned short* d6, unsigned short* d7,
             unsigned short* d8, unsigned short* d9)
{
    const int bi = blockIdx.x;
    const float* s; unsigned short* d; int base;
    if (bi < 512) {
        const int seg = bi >> 6;
        base = (bi & 63) * 1024;
        switch (seg) {
            case 0: s = s0; d = d0; break;
            case 1: s = s1; d = d1; break;
            case 2: s = s2; d = d2; break;
            case 3: s = s3; d = d3; break;
            case 4: s = s4; d = d4; break;
            case 5: s = s5; d = d5; break;
            case 6: s = s6; d = d6; break;
            default: s = s7; d = d7; break;
        }
    } else {
        const int r = bi - 512;
        base = (r & 511) * 1024;
        if (r >> 9) { s = s9; d = d9; } else { s = s8; d = d8; }
    }
    const int i = base + threadIdx.x * 4;
    float4 v = *(const float4*)(s + i);
    ushort4 ov;
    ov.x = f2bfu(v.x); ov.y = f2bfu(v.y); ov.z = f2bfu(v.z); ov.w = f2bfu(v.w);
    *(ushort4*)(d + i) = ov;
}

// ---------------- fused K + V^T projection, 8 waves, wave-specialized K|V ----------------
// R7 structure + 2-deep A prefetch (A-load for k+2 issued at top of step k).
__global__ __launch_bounds__(512, 4)
void proj_kv(const float* __restrict__ enc, const float* __restrict__ ep,
             const __hip_bfloat16* __restrict__ Wk, const float* __restrict__ bk,
             const __hip_bfloat16* __restrict__ Wv, const float* __restrict__ bv,
             __hip_bfloat16* __restrict__ Kout, __hip_bfloat16* __restrict__ Vtout)
{
    __shared__ short Akv[PBM][PLDP];
    __shared__ short Av[PBM][PLDP];
    __shared__ short BkRaw[256 * PLDP];
    __shared__ short BvRaw[256 * PLDP];
    short (*Bk)[PLDP] = (short(*)[PLDP])BkRaw;
    short (*Bv)[PLDP] = (short(*)[PLDP])BvRaw;
    short (*tk)[TLP] = (short(*)[TLP])BkRaw;
    short (*tv)[TLP] = (short(*)[TLP])BvRaw;

    const int tid = threadIdx.x;
    const int m0 = blockIdx.x * PBM;
    const int b = m0 >> 12;
    const int s0 = m0 & (SS - 1);

    const int arr = tid >> 3;
    const int arc = (tid & 7) << 2;
    const long long abase = ((long long)(s0 + arr) * BB + b) * EE + arc;
    const int wr = tid >> 1;
    const int wc = (tid & 1) << 4;
    const long long wbase = (long long)wr * EE + wc;

    const int w = tid >> 6, l = tid & 63;
    const int mat = w >> 2;
    const int wm0 = (w & 1) * 32;
    const int wn0 = ((w >> 1) & 1) * 128;
    const int lr16 = l & 15, lk8 = (l >> 4) * 8;

    f32x4 acc[2][8] = {};

    // 2-deep A prefetch: A-set for k0 (aA/eA) and k0+32 (aB/eB)
    float4 aA = *(const float4*)(enc + abase);
    float4 eA = *(const float4*)(ep + abase);
    float4 aB = *(const float4*)(enc + abase + PBK);
    float4 eB = *(const float4*)(ep + abase + PBK);

    for (int k0 = 0; k0 < EE; k0 += PBK) {
        // W loads for k0 (L2) + A loads for k0+64 (HBM) — issued early
        bf16x8 wk8a = *(const bf16x8*)(Wk + wbase + k0);
        bf16x8 wk8b = *(const bf16x8*)(Wk + wbase + k0 + 8);
        bf16x8 wv8a = *(const bf16x8*)(Wv + wbase + k0);
        bf16x8 wv8b = *(const bf16x8*)(Wv + wbase + k0 + 8);
        float4 aC, eC;
        if (k0 + 2 * PBK < EE) {
            aC = *(const float4*)(enc + abase + k0 + 2 * PBK);
            eC = *(const float4*)(ep + abase + k0 + 2 * PBK);
        }

        bf16x4 pv, pkv;
        pv[0] = (short)f2bfu(aA.x); pv[1] = (short)f2bfu(aA.y);
        pv[2] = (short)f2bfu(aA.z); pv[3] = (short)f2bfu(aA.w);
        pkv[0] = (short)f2bfu(aA.x + eA.x); pkv[1] = (short)f2bfu(aA.y + eA.y);
        pkv[2] = (short)f2bfu(aA.z + eA.z); pkv[3] = (short)f2bfu(aA.w + eA.w);

        __syncthreads();
        *(bf16x4*)&Akv[arr][arc] = pkv;
        *(bf16x4*)&Av[arr][arc]  = pv;
        *(bf16x8*)&Bk[wr][wc]     = wk8a;
        *(bf16x8*)&Bk[wr][wc + 8] = wk8b;
        *(bf16x8*)&Bv[wr][wc]     = wv8a;
        *(bf16x8*)&Bv[wr][wc + 8] = wv8b;
        __syncthreads();

        const short (*Am)[PLDP] = mat ? Av : Akv;
        const short (*Bm)[PLDP] = mat ? Bv : Bk;
        bf16x8 af0 = *(const bf16x8*)&Am[wm0 + lr16][lk8];
        bf16x8 af1 = *(const bf16x8*)&Am[wm0 + 16 + lr16][lk8];
        #pragma unroll
        for (int j = 0; j < 8; ++j) {
            bf16x8 b8 = *(const bf16x8*)&Bm[wn0 + j * 16 + lr16][lk8];
            acc[0][j] = __builtin_amdgcn_mfma_f32_16x16x32_bf16(af0, b8, acc[0][j], 0, 0, 0);
            acc[1][j] = __builtin_amdgcn_mfma_f32_16x16x32_bf16(af1, b8, acc[1][j], 0, 0, 0);
        }

        // static rotation (stays in registers)
        aA = aB; eA = eB;
        aB = aC; eB = eC;
    }

    const float* bias = mat ? bv : bk;
    const int q4 = (l >> 4) * 4;
    #pragma unroll
    for (int h = 0; h < 2; ++h) {
        __syncthreads();
        if (wm0 == h * 32) {
            short (*tile)[TLP] = mat ? tv : tk;
            #pragma unroll
            for (int i = 0; i < 2; ++i) {
                #pragma unroll
                for (int j = 0; j < 8; ++j) {
                    const int n = wn0 + j * 16 + lr16;
                    const float bi = bias[n];
                    #pragma unroll
                    for (int r = 0; r < 4; ++r)
                        tile[i * 16 + q4 + r][n] = (short)f2bfu(acc[i][j][r] + bi);
                }
            }
        }
        __syncthreads();
        #pragma unroll
        for (int it = 0; it < 4; ++it) {
            const int r2 = w * 4 + it;
            ushort4 v = *(const ushort4*)&tk[r2][l * 4];
            *(ushort4*)(Kout + (long long)(m0 + h * 32 + r2) * EE + l * 4) = v;
        }
        #pragma unroll
        for (int nn = 0; nn < 16; ++nn) {
            const int n = w * 32 + nn * 2 + (l >> 5);
            const int s = l & 31;
            unsigned short v = (unsigned short)tv[s][n];
            *((unsigned short*)Vtout + (long long)(b * EE + n) * SS + s0 + h * 32 + s) = v;
        }
    }
}

// ---------------- small MFMA GEMM: 32m x 128n tile, 128 threads ----------------
template<int A1G, int A2Q, int A1BF, int OBF, int RELU>
__global__ __launch_bounds__(128)
void mfma_gemm2(const void* __restrict__ A1v, const float* __restrict__ A2,
                const __hip_bfloat16* __restrict__ Wb, const float* __restrict__ bias,
                void* __restrict__ outv, int N, int K, float scale)
{
    __shared__ short As[32][PLDP];
    __shared__ short Bs[128][PLDP];
    const int tid = threadIdx.x;
    const int m0 = blockIdx.x * 32;
    const int n0 = blockIdx.y * 128;
    const int rr = tid >> 2;
    const int rc = (tid & 3) << 3;
    const int row = m0 + rr;

    long long a2row = 0;
    if (A1G || A2Q) {
        int bq = row / TQ, tq = row - bq * TQ;
        a2row = ((long long)(tq * BB + bq)) * EE;
    }
    const long long a1row = A1G ? a2row : (long long)row * K;

    const int wv = tid >> 6, l = tid & 63;
    const int wm0 = wv * 16;
    const int lr16 = l & 15, lk8 = (l >> 4) * 8;

    f32x4 acc[8] = {};

    for (int k0 = 0; k0 < K; k0 += PBK) {
        bf16x8 apack;
        if (A1BF) {
            apack = *(const bf16x8*)((const __hip_bfloat16*)A1v + a1row + k0 + rc);
        } else {
            const float* A1 = (const float*)A1v;
            float4 a0 = *(const float4*)(A1 + a1row + k0 + rc);
            float4 a1 = *(const float4*)(A1 + a1row + k0 + rc + 4);
            if (A2Q) {
                float4 e0 = *(const float4*)(A2 + a2row + k0 + rc);
                float4 e1 = *(const float4*)(A2 + a2row + k0 + rc + 4);
                a0.x += e0.x; a0.y += e0.y; a0.z += e0.z; a0.w += e0.w;
                a1.x += e1.x; a1.y += e1.y; a1.z += e1.z; a1.w += e1.w;
            }
            apack[0] = (short)f2bfu(a0.x); apack[1] = (short)f2bfu(a0.y);
            apack[2] = (short)f2bfu(a0.z); apack[3] = (short)f2bfu(a0.w);
            apack[4] = (short)f2bfu(a1.x); apack[5] = (short)f2bfu(a1.y);
            apack[6] = (short)f2bfu(a1.z); apack[7] = (short)f2bfu(a1.w);
        }

        bf16x8 wreg[4];
        #pragma unroll
        for (int it = 0; it < 4; ++it)
            wreg[it] = *(const bf16x8*)(Wb + (long long)(n0 + rr + it * 32) * K + k0 + rc);

        __syncthreads();
        *(bf16x8*)&As[rr][rc] = apack;
        #pragma unroll
        for (int it = 0; it < 4; ++it)
            *(bf16x8*)&Bs[rr + it * 32][rc] = wreg[it];
        __syncthreads();

        bf16x8 af = *(const bf16x8*)&As[wm0 + lr16][lk8];
        #pragma unroll
        for (int j = 0; j < 8; ++j) {
            bf16x8 bfr = *(const bf16x8*)&Bs[j * 16 + lr16][lk8];
            acc[j] = __builtin_amdgcn_mfma_f32_16x16x32_bf16(af, bfr, acc[j], 0, 0, 0);
        }
    }

    const int q4 = (l >> 4) * 4;
    #pragma unroll
    for (int j = 0; j < 8; ++j) {
        const int n = n0 + j * 16 + lr16;
        const float bi = bias[n];
        #pragma unroll
        for (int r = 0; r < 4; ++r) {
            float v = (acc[j][r] + bi) * scale;
            if (RELU) v = fmaxf(v, 0.f);
            const long long oidx = (long long)(m0 + wm0 + q4 + r) * N + n;
            if (OBF) ((__hip_bfloat16*)outv)[oidx] = __float2bfloat16(v);
            else     ((float*)outv)[oidx] = v;
        }
    }
}

// ---------------- fused SA QKV projection ----------------
__global__ __launch_bounds__(128)
void qkv_sa(const float* __restrict__ hs1, const float* __restrict__ qp,
            const __hip_bfloat16* __restrict__ Wq, const float* __restrict__ bq,
            const __hip_bfloat16* __restrict__ Wk, const float* __restrict__ bk,
            const __hip_bfloat16* __restrict__ Wv, const float* __restrict__ bv,
            __hip_bfloat16* __restrict__ Qs, __hip_bfloat16* __restrict__ Ks,
            __hip_bfloat16* __restrict__ Vt, int SVT, float qscale)
{
    __shared__ short Aq[32][PLDP];
    __shared__ short Av[32][PLDP];
    __shared__ short Bq[128][PLDP];
    __shared__ short Bk[128][PLDP];
    __shared__ short Bv[128][PLDP];
    const int tid = threadIdx.x;
    const int m0 = blockIdx.x * 32;
    const int n0 = blockIdx.y * 128;
    const int rr = tid >> 2;
    const int rc = (tid & 3) << 3;
    const int row = m0 + rr;
    const int bq_ = row / TQ, tq = row - bq_ * TQ;
    const long long a1row = (long long)row * EE;
    const long long a2row = ((long long)(tq * BB + bq_)) * EE;

    const int wv = tid >> 6, l = tid & 63;
    const int wm0 = wv * 16;
    const int lr16 = l & 15, lk8 = (l >> 4) * 8;

    f32x4 aq[8] = {}, ak[8] = {}, av[8] = {};

    for (int k0 = 0; k0 < EE; k0 += PBK) {
        float4 a0 = *(const float4*)(hs1 + a1row + k0 + rc);
        float4 a1 = *(const float4*)(hs1 + a1row + k0 + rc + 4);
        float4 e0 = *(const float4*)(qp + a2row + k0 + rc);
        float4 e1 = *(const float4*)(qp + a2row + k0 + rc + 4);
        bf16x8 pq, pv;
        pv[0] = (short)f2bfu(a0.x); pv[1] = (short)f2bfu(a0.y);
        pv[2] = (short)f2bfu(a0.z); pv[3] = (short)f2bfu(a0.w);
        pv[4] = (short)f2bfu(a1.x); pv[5] = (short)f2bfu(a1.y);
        pv[6] = (short)f2bfu(a1.z); pv[7] = (short)f2bfu(a1.w);
        pq[0] = (short)f2bfu(a0.x + e0.x); pq[1] = (short)f2bfu(a0.y + e0.y);
        pq[2] = (short)f2bfu(a0.z + e0.z); pq[3] = (short)f2bfu(a0.w + e0.w);
        pq[4] = (short)f2bfu(a1.x + e1.x); pq[5] = (short)f2bfu(a1.y + e1.y);
        pq[6] = (short)f2bfu(a1.z + e1.z); pq[7] = (short)f2bfu(a1.w + e1.w);

        bf16x8 wq8[4], wk8[4], wv8[4];
        #pragma unroll
        for (int it = 0; it < 4; ++it) {
            const long long wrx = (long long)(n0 + rr + it * 32) * EE + k0 + rc;
            wq8[it] = *(const bf16x8*)(Wq + wrx);
            wk8[it] = *(const bf16x8*)(Wk + wrx);
            wv8[it] = *(const bf16x8*)(Wv + wrx);
        }

        __syncthreads();
        *(bf16x8*)&Aq[rr][rc] = pq;
        *(bf16x8*)&Av[rr][rc] = pv;
        #pragma unroll
        for (int it = 0; it < 4; ++it) {
            *(bf16x8*)&Bq[rr + it * 32][rc] = wq8[it];
            *(bf16x8*)&Bk[rr + it * 32][rc] = wk8[it];
            *(bf16x8*)&Bv[rr + it * 32][rc] = wv8[it];
        }
        __syncthreads();

        bf16x8 afq = *(const bf16x8*)&Aq[wm0 + lr16][lk8];
        bf16x8 afv = *(const bf16x8*)&Av[wm0 + lr16][lk8];
        #pragma unroll
        for (int j = 0; j < 8; ++j) {
            bf16x8 b1 = *(const bf16x8*)&Bq[j * 16 + lr16][lk8];
            bf16x8 b2 = *(const bf16x8*)&Bk[j * 16 + lr16][lk8];
            bf16x8 b3 = *(const bf16x8*)&Bv[j * 16 + lr16][lk8];
            aq[j] = __builtin_amdgcn_mfma_f32_16x16x32_bf16(afq, b1, aq[j], 0, 0, 0);
            ak[j] = __builtin_amdgcn_mfma_f32_16x16x32_bf16(afq, b2, ak[j], 0, 0, 0);
            av[j] = __builtin_amdgcn_mfma_f32_16x16x32_bf16(afv, b3, av[j], 0, 0, 0);
        }
    }

    const int q4 = (l >> 4) * 4;
    #pragma unroll
    for (int j = 0; j < 8; ++j) {
        const int n = n0 + j * 16 + lr16;
        const float b1 = bq[n], b2 = bk[n], b3 = bv[n];
        #pragma unroll
        for (int r = 0; r < 4; ++r) {
            const int m = m0 + wm0 + q4 + r;
            Qs[(long long)m * EE + n] = __float2bfloat16((aq[j][r] + b1) * qscale);
            Ks[(long long)m * EE + n] = __float2bfloat16(ak[j][r] + b2);
            const int bb = m / TQ, tt = m - bb * TQ;
            Vt[(long long)(bb * EE + n) * SVT + tt] = __float2bfloat16(av[j][r] + b3);
        }
    }
}

// ---------------- MFMA flash attention: 8 waves, 128 q/block, ONE block per (b,h), KVB=64 ----------------
#define KVB 64

__global__ __launch_bounds__(512, 2)
void flash_mfma(const __hip_bfloat16* __restrict__ Qg,
                const __hip_bfloat16* __restrict__ Kg,
                const __hip_bfloat16* __restrict__ Vtg,
                const float* __restrict__ mask,
                __hip_bfloat16* __restrict__ O,
                int Skv, int SVT)
{
    __shared__ short Ks[2][KVB][40];
    __shared__ short Vs[2][DHH][72];
    const int tid = threadIdx.x;
    const int l = tid & 63;
    const int g = l >> 4, q16 = l & 15;
    const int bh = blockIdx.x;
    const int h = bh & (HH - 1), b = bh >> 3;
    const int q0 = (tid >> 6) * 16;

    int qc = q0 + q16; if (qc >= TQ) qc = TQ - 1;
    const bf16x8 qfrag = *(const bf16x8*)(Qg + ((long long)(b * TQ + qc)) * EE + h * DHH + g * 8);

    const int ksr = tid >> 3;
    const int ksc = (tid & 7) * 4;
    const int vsr = tid >> 4;
    const int vsc = (tid & 15) * 4;
    const long long kbase = ((long long)b * Skv) * EE + h * DHH;
    const long long vbase = ((long long)(b * EE + h * DHH)) * SVT;
    const float* mrowp = mask ? mask + ((long long)bh * TQ + qc) * Skv : nullptr;

    f32x4 oacc[2] = {{0.f,0.f,0.f,0.f},{0.f,0.f,0.f,0.f}};
    float mrun = -1e30f, lrun = 0.f;
    const f32x4 zero = {0.f,0.f,0.f,0.f};

    int s_ld = ksr; if (s_ld >= Skv) s_ld = Skv - 1;
    bf16x4 kreg = *(const bf16x4*)(Kg + kbase + (long long)s_ld * EE + ksc);
    bf16x4 vreg = *(const bf16x4*)(Vtg + vbase + (long long)vsr * SVT + vsc);
    float4 mcur[4], mnx[4];
    if (mrowp) {
        #pragma unroll
        for (int t = 0; t < 4; ++t) mcur[t] = *(const float4*)(mrowp + t * 16 + g * 4);
    }

    const int nround = (Skv + KVB - 1) / KVB;
    for (int r = 0; r < nround; ++r) {
        const int buf = r & 1;
        *(bf16x4*)&Ks[buf][ksr][ksc] = kreg;
        *(bf16x4*)&Vs[buf][vsr][vsc] = vreg;
        if (r + 1 < nround) {
            int sn = (r + 1) * KVB + ksr; if (sn >= Skv) sn = Skv - 1;
            kreg = *(const bf16x4*)(Kg + kbase + (long long)sn * EE + ksc);
            vreg = *(const bf16x4*)(Vtg + vbase + (long long)vsr * SVT + (r + 1) * KVB + vsc);
            if (mrowp) {
                #pragma unroll
                for (int t = 0; t < 4; ++t)
                    mnx[t] = *(const float4*)(mrowp + (r + 1) * KVB + t * 16 + g * 4);
            }
        }
        __syncthreads();

        const int s0 = r * KVB;
        f32x4 sT[4];
        #pragma unroll
        for (int t = 0; t < 4; ++t) {
            bf16x8 kf = *(const bf16x8*)&Ks[buf][t * 16 + q16][g * 8];
            sT[t] = __builtin_amdgcn_mfma_f32_16x16x32_bf16(kf, qfrag, zero, 0, 0, 0);
        }
        float sc[16];
        if (mrowp) {
            #pragma unroll
            for (int t = 0; t < 4; ++t) {
                sc[t*4+0] = sT[t][0] + mcur[t].x; sc[t*4+1] = sT[t][1] + mcur[t].y;
                sc[t*4+2] = sT[t][2] + mcur[t].z; sc[t*4+3] = sT[t][3] + mcur[t].w;
            }
        } else {
            #pragma unroll
            for (int t = 0; t < 4; ++t)
                #pragma unroll
                for (int rg = 0; rg < 4; ++rg) {
                    int s = s0 + t * 16 + g * 4 + rg;
                    sc[t*4+rg] = (s < Skv) ? sT[t][rg] : -1e30f;
                }
        }
        float tmax = sc[0];
        #pragma unroll
        for (int i = 1; i < 16; ++i) tmax = fmaxf(tmax, sc[i]);
        tmax = fmaxf(tmax, __shfl_xor(tmax, 16));
        tmax = fmaxf(tmax, __shfl_xor(tmax, 32));
        const float mn = fmaxf(mrun, tmax);
        const float corr = __expf(mrun - mn);
        mrun = mn;
        float ps = 0.f;
        float pe[16];
        #pragma unroll
        for (int i = 0; i < 16; ++i) {
            pe[i] = __expf(sc[i] - mn);
            ps += pe[i];
        }
        ps += __shfl_xor(ps, 16);
        ps += __shfl_xor(ps, 32);
        lrun = lrun * corr + ps;
        #pragma unroll
        for (int rg = 0; rg < 4; ++rg) {
            float c = __shfl(corr, g * 4 + rg);
            oacc[0][rg] *= c;
            oacc[1][rg] *= c;
        }
        #pragma unroll
        for (int sb = 0; sb < 2; ++sb) {
            bf16x8 pfrag;
            #pragma unroll
            for (int e = 0; e < 4; ++e) {
                pfrag[e]     = (short)f2bfu(pe[(2*sb)*4 + e]);
                pfrag[e + 4] = (short)f2bfu(pe[(2*sb+1)*4 + e]);
            }
            #pragma unroll
            for (int T = 0; T < 2; ++T) {
                bf16x4 v0 = *(const bf16x4*)&Vs[buf][T * 16 + q16][sb * 32 + g * 4];
                bf16x4 v1 = *(const bf16x4*)&Vs[buf][T * 16 + q16][sb * 32 + 16 + g * 4];
                bf16x8 vf;
                vf[0] = v0[0]; vf[1] = v0[1]; vf[2] = v0[2]; vf[3] = v0[3];
                vf[4] = v1[0]; vf[5] = v1[1]; vf[6] = v1[2]; vf[7] = v1[3];
                oacc[T] = __builtin_amdgcn_mfma_f32_16x16x32_bf16(pfrag, vf, oacc[T], 0, 0, 0);
            }
        }
        #pragma unroll
        for (int t = 0; t < 4; ++t) mcur[t] = mnx[t];
        __syncthreads();
    }

    float linv[4];
    #pragma unroll
    for (int rg = 0; rg < 4; ++rg)
        linv[rg] = 1.f / __shfl(lrun, g * 4 + rg);
    #pragma unroll
    for (int rg = 0; rg < 4; ++rg) {
        const int q = q0 + g * 4 + rg;
        if (q < TQ) {
            __hip_bfloat16* op = O + ((long long)(b * TQ + q)) * EE + h * DHH + q16;
            op[0]  = __float2bfloat16(oacc[0][rg] * linv[rg]);
            op[16] = __float2bfloat16(oacc[1][rg] * linv[rg]);
        }
    }
}

// ---------------- LayerNorm ----------------
template<int GATHER_RES, int OUT_T, int OUT_BF>
__global__ __launch_bounds__(256)
void ln_kernel(const float* __restrict__ res, const float* __restrict__ x,
               const float* __restrict__ gam, const float* __restrict__ bet,
               float* __restrict__ out, __hip_bfloat16* __restrict__ outb)
{
    __shared__ float r1[4], r2[4];
    const int m = blockIdx.x;
    const int k = threadIdx.x;
    const int b = m / TQ, t = m - b * TQ;
    const long long roff = GATHER_RES ? ((long long)(t * BB + b)) * EE : (long long)m * EE;
    float v = res[roff + k] + x[(long long)m * EE + k];
    float s = v;
    #pragma unroll
    for (int off = 32; off; off >>= 1) s += __shfl_down(s, off);
    if ((k & 63) == 0) r1[k >> 6] = s;
    __syncthreads();
    const float mu = (r1[0] + r1[1] + r1[2] + r1[3]) * (1.0f / EE);
    const float d = v - mu;
    float s2 = d * d;
    #pragma unroll
    for (int off = 32; off; off >>= 1) s2 += __shfl_down(s2, off);
    if ((k & 63) == 0) r2[k >> 6] = s2;
    __syncthreads();
    const float var = (r2[0] + r2[1] + r2[2] + r2[3]) * (1.0f / EE);
    const float o = d * rsqrtf(var + LNEPS) * gam[k] + bet[k];
    const long long ooff = OUT_T ? ((long long)(t * BB + b)) * EE : (long long)m * EE;
    out[ooff + k] = o;
    if (OUT_BF) outb[(long long)m * EE + k] = __float2bfloat16(o);
}

extern "C" void kernel_launch(void* const* d_in, const int* in_sizes, int n_in,
                              void* d_out, int out_size, void* d_ws, size_t ws_size,
                              hipStream_t stream)
{
    const float* hs    = (const float*)d_in[0];
    const float* qp    = (const float*)d_in[1];
    const float* enc   = (const float*)d_in[2];
    const float* ep    = (const float*)d_in[3];
    const float* mask  = (const float*)d_in[4];
    const float* ca_wq = (const float*)d_in[5];  const float* ca_bq = (const float*)d_in[6];
    const float* ca_wk = (const float*)d_in[7];  const float* ca_bk = (const float*)d_in[8];
    const float* ca_wv = (const float*)d_in[9];  const float* ca_bv = (const float*)d_in[10];
    const float* ca_wo = (const float*)d_in[11]; const float* ca_bo = (const float*)d_in[12];
    const float* sa_wq = (const float*)d_in[13]; const float* sa_bq = (const float*)d_in[14];
    const float* sa_wk = (const float*)d_in[15]; const float* sa_bk = (const float*)d_in[16];
    const float* sa_wv = (const float*)d_in[17]; const float* sa_bv = (const float*)d_in[18];
    const float* sa_wo = (const float*)d_in[19]; const float* sa_bo = (const float*)d_in[20];
    const float* ln1_g = (const float*)d_in[21]; const float* ln1_b = (const float*)d_in[22];
    const float* ln2_g = (const float*)d_in[23]; const float* ln2_b = (const float*)d_in[24];
    const float* ln3_g = (const float*)d_in[25]; const float* ln3_b = (const float*)d_in[26];
    const float* fc1_w = (const float*)d_in[27]; const float* fc1_b = (const float*)d_in[28];
    const float* fc2_w = (const float*)d_in[29]; const float* fc2_b = (const float*)d_in[30];

    const int MQ = BB * TQ;   // 3200
    const int MK = BB * SS;   // 131072
    const int SVT2 = 128;

    size_t off = 0;
    char* base = (char*)d_ws;
    auto alloc = [&](size_t bytes) -> void* {
        void* p = base + off; off = (off + bytes + 255) & ~(size_t)255; return p;
    };
    __hip_bfloat16* Kc  = (__hip_bfloat16*)alloc((size_t)MK * EE * 2);
    __hip_bfloat16* Vt  = (__hip_bfloat16*)alloc((size_t)BB * EE * SS * 2);
    __hip_bfloat16* Qc  = (__hip_bfloat16*)alloc((size_t)MQ * EE * 2);
    __hip_bfloat16* Qs  = (__hip_bfloat16*)alloc((size_t)MQ * EE * 2);
    __hip_bfloat16* Ks2 = (__hip_bfloat16*)alloc((size_t)MQ * EE * 2);
    __hip_bfloat16* Vt2 = (__hip_bfloat16*)alloc((size_t)BB * EE * SVT2 * 2);
    __hip_bfloat16* Wq1 = (__hip_bfloat16*)alloc((size_t)EE * EE * 2);
    __hip_bfloat16* Wkb = (__hip_bfloat16*)alloc((size_t)EE * EE * 2);
    __hip_bfloat16* Wvb = (__hip_bfloat16*)alloc((size_t)EE * EE * 2);
    __hip_bfloat16* Wo1 = (__hip_bfloat16*)alloc((size_t)EE * EE * 2);
    __hip_bfloat16* Wq2 = (__hip_bfloat16*)alloc((size_t)EE * EE * 2);
    __hip_bfloat16* Wk2 = (__hip_bfloat16*)alloc((size_t)EE * EE * 2);
    __hip_bfloat16* Wv2 = (__hip_bfloat16*)alloc((size_t)EE * EE * 2);
    __hip_bfloat16* Wo2 = (__hip_bfloat16*)alloc((size_t)EE * EE * 2);
    __hip_bfloat16* Wf1 = (__hip_bfloat16*)alloc((size_t)FF * EE * 2);
    __hip_bfloat16* Wf2 = (__hip_bfloat16*)alloc((size_t)EE * FF * 2);
    __hip_bfloat16* hs2b= (__hip_bfloat16*)alloc((size_t)MQ * EE * 2);
    __hip_bfloat16* h1b = (__hip_bfloat16*)alloc((size_t)MQ * FF * 2);
    __hip_bfloat16* attO  = (__hip_bfloat16*)alloc((size_t)MQ * EE * 2);
    __hip_bfloat16* attO2 = (__hip_bfloat16*)alloc((size_t)MQ * EE * 2);
    float* xproj = (float*)alloc((size_t)MQ * EE * 4);
    float* hs1   = (float*)alloc((size_t)MQ * EE * 4);
    float* xpro2 = (float*)alloc((size_t)MQ * EE * 4);
    float* hs2   = (float*)alloc((size_t)MQ * EE * 4);
    float* xffn  = (float*)alloc((size_t)MQ * EE * 4);

    const float qscale = 0.17677669529663687f;
    dim3 blk(256);

    cvt_all<<<dim3(1536), blk, 0, stream>>>(
        ca_wq, ca_wk, ca_wv, ca_wo, sa_wq, sa_wk, sa_wv, sa_wo, fc1_w, fc2_w,
        (unsigned short*)Wq1, (unsigned short*)Wkb, (unsigned short*)Wvb,
        (unsigned short*)Wo1, (unsigned short*)Wq2, (unsigned short*)Wk2,
        (unsigned short*)Wv2, (unsigned short*)Wo2, (unsigned short*)Wf1,
        (unsigned short*)Wf2);

    // ---- cross-attention ----
    mfma_gemm2<1,1,0,1,0><<<dim3(MQ/32, 2), dim3(128), 0, stream>>>(hs, qp, Wq1, ca_bq, Qc, EE, EE, qscale);
    proj_kv<<<dim3(MK/PBM), dim3(512), 0, stream>>>(enc, ep, Wkb, ca_bk, Wvb, ca_bv, Kc, Vt);
    flash_mfma<<<dim3(BB*HH), dim3(512), 0, stream>>>(Qc, Kc, Vt, mask, attO, SS, SS);
    mfma_gemm2<0,0,1,0,0><<<dim3(MQ/32, 2), dim3(128), 0, stream>>>(attO, nullptr, Wo1, ca_bo, xproj, EE, EE, 1.f);
    ln_kernel<1,0,0><<<dim3(MQ), blk, 0, stream>>>(hs, xproj, ln1_g, ln1_b, hs1, nullptr);

    // ---- self-attention ----
    qkv_sa<<<dim3(MQ/32, 2), dim3(128), 0, stream>>>(hs1, qp, Wq2, sa_bq, Wk2, sa_bk, Wv2, sa_bv,
                                                     Qs, Ks2, Vt2, SVT2, qscale);
    flash_mfma<<<dim3(BB*HH), dim3(512), 0, stream>>>(Qs, Ks2, Vt2, nullptr, attO2, TQ, SVT2);
    mfma_gemm2<0,0,1,0,0><<<dim3(MQ/32, 2), dim3(128), 0, stream>>>(attO2, nullptr, Wo2, sa_bo, xpro2, EE, EE, 1.f);
    ln_kernel<0,0,1><<<dim3(MQ), blk, 0, stream>>>(hs1, xpro2, ln2_g, ln2_b, hs2, hs2b);

    // ---- FFN ----
    mfma_gemm2<0,0,1,1,1><<<dim3(MQ/32, FF/128), dim3(128), 0, stream>>>(hs2b, nullptr, Wf1, fc1_b, h1b, FF, EE, 1.f);
    mfma_gemm2<0,0,1,0,0><<<dim3(MQ/32, 2), dim3(128), 0, stream>>>(h1b, nullptr, Wf2, fc2_b, xffn, EE, FF, 1.f);
    ln_kernel<0,1,0><<<dim3(MQ), blk, 0, stream>>>(hs2, xffn, ln3_g, ln3_b, (float*)d_out, nullptr);

    (void)in_sizes; (void)n_in; (void)out_size; (void)ws_size;
}